// Round 1
// baseline (617.725 us; speedup 1.0000x reference)
//
#include <hip/hip_runtime.h>
#include <cstdint>

// ---------------- problem constants ----------------
// QG=8, N=1024, DIM=512, H=8, D=64; rows per tensor = 8192; HQ = H*QG = 64
// f layout: [h][qg][n][d]  -> idx = (h*8+qg)*65536 + n*64 + d

// ---------------- workspace layout (floats) ----------------
#define WS_FQ      0LL
#define WS_FK      4194304LL
#define WS_FV      8388608LL          // also reused as out_attn after K4
#define WS_LNSTAT  12582912LL         // [3][8192][2] (mu, rsigma)
#define WS_INVNQ   12632064LL         // [64][1024]
#define WS_INVNK   12697600LL
#define WS_QMEAN   12763136LL
#define WS_KMEAN   12828672LL
#define WS_VQS     12894208LL         // [64][64] per-(hq) col sums of f_q
#define WS_VQSS    12898304LL
#define WS_VKS     12902400LL
#define WS_VKSS    12906496LL
#define WS_WGATE   12910592LL         // [8] (+pad)
#define WS_MBUF    12910656LL         // [64][64][64]
#define WS_CBUF    13172800LL
#define WS_MCP     13434944LL         // [2][4][64][4096] split-K partials
#define WS_OATT    WS_FV

__device__ __forceinline__ float wsum(float v) {
#pragma unroll
    for (int m = 32; m; m >>= 1) v += __shfl_xor(v, m, 64);
    return v;
}
__device__ __forceinline__ float rdlane(float v, int l) {
    return __int_as_float(__builtin_amdgcn_readlane(__float_as_int(v), l));
}

// ---------------- K0: LN row stats over DIM=512 ----------------
__global__ __launch_bounds__(256) void k_lnstats(
    const float* __restrict__ q, const float* __restrict__ k,
    const float* __restrict__ v, float* __restrict__ ws) {
    int wid = threadIdx.x >> 6, lane = threadIdx.x & 63;
    int row = blockIdx.x * 4 + wid;            // 0..24575
    int t = row >> 13, r = row & 8191;
    const float* src = (t == 0) ? q : ((t == 1) ? k : v);
    const float4* p = (const float4*)(src + (size_t)r * 512) + lane * 2;
    float4 a = p[0], b = p[1];
    float s = a.x + a.y + a.z + a.w + b.x + b.y + b.z + b.w;
    float ss = a.x * a.x + a.y * a.y + a.z * a.z + a.w * a.w +
               b.x * b.x + b.y * b.y + b.z * b.z + b.w * b.w;
    s = wsum(s); ss = wsum(ss);
    if (lane == 0) {
        float mu = s * (1.f / 512.f);
        float var = ss * (1.f / 512.f) - mu * mu;
        ws[WS_LNSTAT + (size_t)row * 2] = mu;
        ws[WS_LNSTAT + (size_t)row * 2 + 1] = rsqrtf(var + 1e-5f);
    }
}

// ---------------- K1/K6: tiled fp32 GEMM, 128x128 tile, 8x8 micro ----------------
// MODE 0: A' = LN(A) on the fly, scatter-store into f[h][qg][n][d]
// MODE 1: plain A, +bias, row-major store
template <int MODE>
__global__ __launch_bounds__(256) void k_gemm(
    const float* __restrict__ A, const float* __restrict__ W,
    const float* __restrict__ lnst, const float* __restrict__ lng,
    const float* __restrict__ lnb, const float* __restrict__ bias,
    float* __restrict__ out) {
    __shared__ float As[32][132];
    __shared__ float Bs[32][132];
    int tid = threadIdx.x;
    int m0 = blockIdx.y * 128, c0 = blockIdx.x * 128;
    float acc[8][8];
#pragma unroll
    for (int i = 0; i < 8; i++)
#pragma unroll
        for (int j = 0; j < 8; j++) acc[i][j] = 0.f;
    int tm = (tid & 15) * 8, tn = (tid >> 4) * 8;

    for (int k0 = 0; k0 < 512; k0 += 32) {
#pragma unroll
        for (int i = 0; i < 4; i++) {
            int idx = tid + 256 * i;
            int mi = idx >> 3, kq = (idx & 7) * 4;
            int gm = m0 + mi;
            float4 x = *(const float4*)(A + (size_t)gm * 512 + k0 + kq);
            if (MODE == 0) {
                float mu = lnst[gm * 2], rs = lnst[gm * 2 + 1];
                x.x = (x.x - mu) * rs * lng[k0 + kq + 0] + lnb[k0 + kq + 0];
                x.y = (x.y - mu) * rs * lng[k0 + kq + 1] + lnb[k0 + kq + 1];
                x.z = (x.z - mu) * rs * lng[k0 + kq + 2] + lnb[k0 + kq + 2];
                x.w = (x.w - mu) * rs * lng[k0 + kq + 3] + lnb[k0 + kq + 3];
            }
            As[kq + 0][mi] = x.x; As[kq + 1][mi] = x.y;
            As[kq + 2][mi] = x.z; As[kq + 3][mi] = x.w;
        }
#pragma unroll
        for (int i = 0; i < 4; i++) {
            int idx = tid + 256 * i;
            int kr = idx >> 5, c4 = (idx & 31) * 4;
            *(float4*)&Bs[kr][c4] = *(const float4*)(W + (size_t)(k0 + kr) * 512 + c0 + c4);
        }
        __syncthreads();
#pragma unroll 8
        for (int kk = 0; kk < 32; kk++) {
            float a[8], b[8];
            *(float4*)(a) = *(float4*)&As[kk][tm];
            *(float4*)(a + 4) = *(float4*)&As[kk][tm + 4];
            *(float4*)(b) = *(float4*)&Bs[kk][tn];
            *(float4*)(b + 4) = *(float4*)&Bs[kk][tn + 4];
#pragma unroll
            for (int i = 0; i < 8; i++)
#pragma unroll
                for (int j = 0; j < 8; j++) acc[i][j] = fmaf(a[i], b[j], acc[i][j]);
        }
        __syncthreads();
    }
#pragma unroll
    for (int i = 0; i < 8; i++) {
        int gm = m0 + tm + i;
        if (MODE == 0) {
            int qg = gm >> 10, n = gm & 1023;
#pragma unroll
            for (int jj = 0; jj < 8; jj += 4) {
                int c = c0 + tn + jj;
                int h = c >> 6, d = c & 63;
                float4 o = {acc[i][jj], acc[i][jj + 1], acc[i][jj + 2], acc[i][jj + 3]};
                *(float4*)(out + (size_t)h * 524288 + (size_t)qg * 65536 + (size_t)n * 64 + d) = o;
            }
        } else {
#pragma unroll
            for (int jj = 0; jj < 8; jj += 4) {
                int c = c0 + tn + jj;
                float4 o = {acc[i][jj] + bias[c], acc[i][jj + 1] + bias[c + 1],
                            acc[i][jj + 2] + bias[c + 2], acc[i][jj + 3] + bias[c + 3]};
                *(float4*)(out + (size_t)gm * 512 + c) = o;
            }
        }
    }
}

// ---------------- K2: per-row norm/mean of f_q,f_k + per-(hq) column sums ----------------
__global__ __launch_bounds__(256) void k_fstats(float* __restrict__ ws) {
    int b = blockIdx.x;
    int t = b >> 6, hq = b & 63;
    const float* f = ws + (t ? WS_FK : WS_FQ) + (size_t)hq * 65536;
    float* invn = ws + (t ? WS_INVNK : WS_INVNQ) + hq * 1024;
    float* mean = ws + (t ? WS_KMEAN : WS_QMEAN) + hq * 1024;
    int wid = threadIdx.x >> 6, lane = threadIdx.x & 63;
    float ls = 0.f, lss = 0.f;
    for (int n = wid; n < 1024; n += 4) {
        float x = f[n * 64 + lane];
        ls += x; lss += x * x;
        float s = wsum(x);
        float ss = wsum(x * x);
        if (lane == 0) { invn[n] = rsqrtf(ss); mean[n] = s * (1.f / 64.f); }
    }
    __shared__ float red[8][64];
    red[wid][lane] = ls; red[4 + wid][lane] = lss;
    __syncthreads();
    if (wid == 0) {
        float a = red[0][lane] + red[1][lane] + red[2][lane] + red[3][lane];
        float c = red[4][lane] + red[5][lane] + red[6][lane] + red[7][lane];
        ws[(t ? WS_VKS : WS_VQS) + hq * 64 + lane] = a;
        ws[(t ? WS_VKSS : WS_VQSS) + hq * 64 + lane] = c;
    }
}

// ---------------- K3: gate MLP + variance penalty (1 wave) ----------------
__global__ __launch_bounds__(64) void k_gate(
    const float* __restrict__ pw1, const float* __restrict__ pb1,
    const float* __restrict__ plg, const float* __restrict__ plb,
    const float* __restrict__ pw2, const float* __restrict__ pb2,
    float* __restrict__ ws) {
    int lane = threadIdx.x;
    float Sq = 0, SSq = 0, Sk = 0, SSk = 0;
    for (int i = 0; i < 64; i++) {
        Sq += ws[WS_VQS + i * 64 + lane];
        SSq += ws[WS_VQSS + i * 64 + lane];
        Sk += ws[WS_VKS + i * 64 + lane];
        SSk += ws[WS_VKSS + i * 64 + lane];
    }
    const float NR = 65536.f;
    float stdq = sqrtf((SSq - Sq * Sq / NR) / (NR - 1.f) + 1e-4f);
    float stdk = sqrtf((SSk - Sk * Sk / NR) / (NR - 1.f) + 1e-4f);
    float vpen = (wsum(fmaxf(1.f - stdq, 0.f)) + wsum(fmaxf(1.f - stdk, 0.f))) * (1.f / 64.f);

    __shared__ float xg[8][128];
    __shared__ float w1[128][64];
    for (int h = 0; h < 8; h++) {
        float sq = 0, sk = 0;
        for (int g = 0; g < 8; g++) {
            sq += ws[WS_VQS + (h * 8 + g) * 64 + lane];
            sk += ws[WS_VKS + (h * 8 + g) * 64 + lane];
        }
        xg[h][lane] = sq * (1.f / 8192.f);
        xg[h][64 + lane] = sk * (1.f / 8192.f);
    }
    for (int i = 0; i < 128; i++) w1[i][lane] = pw1[i * 64 + lane];
    __syncthreads();
    float gammav = plg[lane], betav = plb[lane], w2v = pw2[lane];
    for (int h = 0; h < 8; h++) {
        float y = pb1[lane];
        for (int i = 0; i < 128; i++) y = fmaf(xg[h][i], w1[i][lane], y);
        float mu = wsum(y) * (1.f / 64.f);
        float dv = y - mu;
        float var = wsum(dv * dv) * (1.f / 64.f);
        float z = dv * rsqrtf(var + 1e-5f) * gammav + betav;
        float r = fmaxf(z, 0.f);
        float sdot = wsum(r * w2v);
        if (lane == 0) {
            float wv = 1.f / (1.f + expf(-(sdot + pb2[0])));
            ws[WS_WGATE + h] = wv / (1.f + vpen);
        }
    }
}

// ---------------- K4: build M,C (64x64 per hq), split-K over 4 parts ----------------
__global__ __launch_bounds__(256) void k_mc(float* __restrict__ ws) {
    int part = blockIdx.x, hq = blockIdx.y;
    const float* fk = ws + WS_FK + (size_t)hq * 65536;
    const float* fv = ws + WS_FV + (size_t)hq * 65536;
    const float* invk = ws + WS_INVNK + hq * 1024;
    const float* kmg = ws + WS_KMEAN + hq * 1024;
    __shared__ float fks[64][68], fkc[64][68], fvs[64][68];
    int tid = threadIdx.x;
    int e2 = (tid & 31) * 2, d0 = (tid >> 5) * 8;
    float am[2][8], ac[2][8];
#pragma unroll
    for (int r = 0; r < 2; r++)
#pragma unroll
        for (int j = 0; j < 8; j++) { am[r][j] = 0.f; ac[r][j] = 0.f; }

    for (int ch = 0; ch < 4; ch++) {
        int m0 = part * 256 + ch * 64;
        {
            int mr = tid >> 2, cq = (tid & 3) * 16;
            float inv = invk[m0 + mr], km = kmg[m0 + mr];
            const float* fkr = fk + (size_t)(m0 + mr) * 64 + cq;
            const float* fvr = fv + (size_t)(m0 + mr) * 64 + cq;
#pragma unroll
            for (int j = 0; j < 4; j++) {
                float4 kv = *(const float4*)(fkr + j * 4);
                float4 vv = *(const float4*)(fvr + j * 4);
                *(float4*)&fvs[mr][cq + j * 4] = vv;
                float4 ksv = {kv.x * inv, kv.y * inv, kv.z * inv, kv.w * inv};
                float4 kcv = {kv.x - km, kv.y - km, kv.z - km, kv.w - km};
                *(float4*)&fks[mr][cq + j * 4] = ksv;
                *(float4*)&fkc[mr][cq + j * 4] = kcv;
            }
        }
        __syncthreads();
#pragma unroll 4
        for (int mm = 0; mm < 64; mm++) {
            float2 as = *(float2*)&fks[mm][e2];
            float2 av = *(float2*)&fkc[mm][e2];
            float b[8];
            *(float4*)(b) = *(float4*)&fvs[mm][d0];
            *(float4*)(b + 4) = *(float4*)&fvs[mm][d0 + 4];
#pragma unroll
            for (int j = 0; j < 8; j++) {
                am[0][j] = fmaf(as.x, b[j], am[0][j]);
                am[1][j] = fmaf(as.y, b[j], am[1][j]);
                ac[0][j] = fmaf(av.x, b[j], ac[0][j]);
                ac[1][j] = fmaf(av.y, b[j], ac[1][j]);
            }
        }
        __syncthreads();
    }
    float* pm = ws + WS_MCP + ((size_t)(0 * 4 + part) * 64 + hq) * 4096;
    float* pc = ws + WS_MCP + ((size_t)(1 * 4 + part) * 64 + hq) * 4096;
#pragma unroll
    for (int r = 0; r < 2; r++) {
        *(float4*)(pm + (e2 + r) * 64 + d0) = *(float4*)&am[r][0];
        *(float4*)(pm + (e2 + r) * 64 + d0 + 4) = *(float4*)&am[r][4];
        *(float4*)(pc + (e2 + r) * 64 + d0) = *(float4*)&ac[r][0];
        *(float4*)(pc + (e2 + r) * 64 + d0 + 4) = *(float4*)&ac[r][4];
    }
}

// ---------------- K4b: reduce split-K partials ----------------
__global__ __launch_bounds__(256) void k_mcred(float* __restrict__ ws) {
    int cell = blockIdx.x * 256 + threadIdx.x;   // < 524288
    int mat = cell >> 18, rem = cell & 262143;
    float s = 0.f;
#pragma unroll
    for (int p = 0; p < 4; p++) s += ws[WS_MCP + (size_t)(mat * 4 + p) * 262144 + rem];
    ws[WS_MBUF + (size_t)mat * 262144 + rem] = s;
}

// ---------------- K5: out_attn = (1-w)/nq * fq@M + (w/64) * (fq-qmean)@C ----------------
__global__ __launch_bounds__(256) void k_apply(float* __restrict__ ws) {
    int nt = blockIdx.x, hq = blockIdx.y;
    int h = hq >> 3, qg = hq & 7;
    __shared__ float Ms[64][68], Cs[64][68];
    int tid = threadIdx.x;
#pragma unroll
    for (int i = 0; i < 4; i++) {
        int idx = tid + 256 * i;
        int e = idx >> 4, d4 = (idx & 15) * 4;
        *(float4*)&Ms[e][d4] = *(const float4*)(ws + WS_MBUF + (size_t)hq * 4096 + e * 64 + d4);
        *(float4*)&Cs[e][d4] = *(const float4*)(ws + WS_CBUF + (size_t)hq * 4096 + e * 64 + d4);
    }
    float w = ws[WS_WGATE + h];
    float c1 = 1.f - w, c2 = w * (1.f / 64.f);
    __syncthreads();
    int wid = tid >> 6, lane = tid & 63;
    float colC = 0.f;
#pragma unroll 16
    for (int e = 0; e < 64; e++) colC += Cs[e][lane];

    const float* fq = ws + WS_FQ + (size_t)hq * 65536;
    const float* qm = ws + WS_QMEAN + hq * 1024;
    const float* inv = ws + WS_INVNQ + hq * 1024;
    float* oat = ws + WS_OATT;
    int nb = nt * 128 + wid * 32;
    for (int g = 0; g < 8; g++) {
        int n = nb + g * 4;
        float a0 = fq[(n + 0) * 64 + lane];
        float a1 = fq[(n + 1) * 64 + lane];
        float a2 = fq[(n + 2) * 64 + lane];
        float a3 = fq[(n + 3) * 64 + lane];
        float m0a = 0, m1a = 0, m2a = 0, m3a = 0;
        float c0a = 0, c1a = 0, c2a = 0, c3a = 0;
#pragma unroll 16
        for (int e = 0; e < 64; e++) {
            float mv = Ms[e][lane], cv = Cs[e][lane];
            float b0 = rdlane(a0, e), b1 = rdlane(a1, e);
            float b2 = rdlane(a2, e), b3 = rdlane(a3, e);
            m0a = fmaf(b0, mv, m0a); m1a = fmaf(b1, mv, m1a);
            m2a = fmaf(b2, mv, m2a); m3a = fmaf(b3, mv, m3a);
            c0a = fmaf(b0, cv, c0a); c1a = fmaf(b1, cv, c1a);
            c2a = fmaf(b2, cv, c2a); c3a = fmaf(b3, cv, c3a);
        }
#pragma unroll
        for (int r = 0; r < 4; r++) {
            float ma = (r == 0) ? m0a : (r == 1) ? m1a : (r == 2) ? m2a : m3a;
            float ca = (r == 0) ? c0a : (r == 1) ? c1a : (r == 2) ? c2a : c3a;
            float qmv = qm[n + r], invv = inv[n + r];
            float val = c1 * invv * ma + c2 * (ca - qmv * colC);
            oat[((size_t)qg * 1024 + n + r) * 512 + h * 64 + lane] = val;
        }
    }
}

// ---------------- host launch ----------------
extern "C" void kernel_launch(void* const* d_in, const int* in_sizes, int n_in,
                              void* d_out, int out_size, void* d_ws, size_t ws_size,
                              hipStream_t stream) {
    (void)in_sizes; (void)n_in; (void)out_size; (void)ws_size;
    const float* q = (const float*)d_in[0];
    const float* k = (const float*)d_in[1];
    const float* v = (const float*)d_in[2];
    const float* ln_g = (const float*)d_in[3];
    const float* ln_b = (const float*)d_in[4];
    const float* w_in = (const float*)d_in[5];
    const float* p_w1 = (const float*)d_in[6];
    const float* p_b1 = (const float*)d_in[7];
    const float* p_ln_g = (const float*)d_in[8];
    const float* p_ln_b = (const float*)d_in[9];
    const float* p_w2 = (const float*)d_in[10];
    const float* p_b2 = (const float*)d_in[11];
    const float* w_out = (const float*)d_in[12];
    const float* b_out = (const float*)d_in[13];
    float* ws = (float*)d_ws;
    float* out = (float*)d_out;

    k_lnstats<<<6144, 256, 0, stream>>>(q, k, v, ws);
    k_gemm<0><<<dim3(4, 64), 256, 0, stream>>>(q, w_in, ws + WS_LNSTAT, ln_g, ln_b, nullptr, ws + WS_FQ);
    k_gemm<0><<<dim3(4, 64), 256, 0, stream>>>(k, w_in, ws + WS_LNSTAT + 16384, ln_g, ln_b, nullptr, ws + WS_FK);
    k_gemm<0><<<dim3(4, 64), 256, 0, stream>>>(v, w_in, ws + WS_LNSTAT + 32768, ln_g, ln_b, nullptr, ws + WS_FV);
    k_fstats<<<128, 256, 0, stream>>>(ws);
    k_gate<<<1, 64, 0, stream>>>(p_w1, p_b1, p_ln_g, p_ln_b, p_w2, p_b2, ws);
    k_mc<<<dim3(4, 64), 256, 0, stream>>>(ws);
    k_mcred<<<2048, 256, 0, stream>>>(ws);
    k_apply<<<dim3(8, 64), 256, 0, stream>>>(ws);
    k_gemm<1><<<dim3(4, 64), 256, 0, stream>>>(ws + WS_OATT, w_out, nullptr, nullptr, nullptr, b_out, out);
}

// Round 2
// 192.664 us; speedup vs baseline: 3.2062x; 3.2062x over previous
//
#include <hip/hip_runtime.h>
#include <cstdint>

// ---------------- problem constants ----------------
// QG=8, N=1024, DIM=512, H=8, D=64; rows/tensor=8192; HQ=64
// f layout: [hq][n][d] (bf16), idx = hq*65536 + n*64 + d

typedef unsigned short u16;
typedef unsigned int u32;
typedef __attribute__((ext_vector_type(8))) unsigned short u16x8;
typedef __attribute__((ext_vector_type(4))) unsigned short u16x4;
typedef __attribute__((ext_vector_type(8))) short short8;
typedef __attribute__((ext_vector_type(4))) float floatx4;

// ---------------- workspace layout (float offsets) ----------------
#define WS_XBF     0LL          // bf16 [24576][512]  (q,k,v stacked)
#define WS_MCP     0LL          // f32 [2][4][64][4096]  (aliases XBF, used after)
#define WS_OATT    2097152LL    // bf16 [8192][512]      (aliases XBF, used after)
#define WS_WPT     6291456LL    // bf16 W'T [512][512]
#define WS_WOT     6422528LL    // bf16 w_outT [512][512]
#define WS_U       6553600LL    // f32 [512]  g@W_in
#define WS_CB      6554112LL    // f32 [512]  b@W_in
#define WS_LNST    6554624LL    // f32 [24576][2] (mu, rsigma)
#define WS_FQ      6603776LL    // bf16 [64][1024][64]
#define WS_FK      8700928LL
#define WS_FV      10798080LL
#define WS_INVNQ   12895232LL   // f32 [64][1024]
#define WS_INVNK   12960768LL
#define WS_QMEAN   13026304LL
#define WS_KMEAN   13091840LL
#define WS_COLP    13157376LL   // f32 [2][64][8][64][2] (sum, sumsq)
#define WS_WGATE   13288448LL   // f32 [8] (+pad)
#define WS_MBUF    13288512LL   // f32 [64][64][64]
#define WS_WTF32   13288512LL   // f32 WT [512][512] (aliases MBUF, prep-phase only)
#define WS_CBUF    13550656LL   // f32 [64][64][64]   (end = 13812800 fl = 55.3 MB)

__device__ __forceinline__ float wsum(float v) {
#pragma unroll
    for (int m = 32; m; m >>= 1) v += __shfl_xor(v, m, 64);
    return v;
}
__device__ __forceinline__ float rdlane(float v, int l) {
    return __int_as_float(__builtin_amdgcn_readlane(__float_as_int(v), l));
}
__device__ __forceinline__ u16 f2bf(float f) {
    u32 u = __float_as_uint(f);
    u32 r = u + 0x7fffu + ((u >> 16) & 1u);
    return (u16)(r >> 16);
}
__device__ __forceinline__ float bf2f(u16 u) {
    return __uint_as_float(((u32)u) << 16);
}

// ---------------- K0: LN row stats over DIM=512 + bf16 copy ----------------
__global__ __launch_bounds__(256) void k_lnstats(
    const float* __restrict__ q, const float* __restrict__ k,
    const float* __restrict__ v, float* __restrict__ ws) {
    int wid = threadIdx.x >> 6, lane = threadIdx.x & 63;
    int row = blockIdx.x * 4 + wid;            // 0..24575
    int t = row >> 13, r = row & 8191;
    const float* src = (t == 0) ? q : ((t == 1) ? k : v);
    const float4* p = (const float4*)(src + (size_t)r * 512) + lane * 2;
    float4 a = p[0], b = p[1];
    u16x8 o;
    o[0] = f2bf(a.x); o[1] = f2bf(a.y); o[2] = f2bf(a.z); o[3] = f2bf(a.w);
    o[4] = f2bf(b.x); o[5] = f2bf(b.y); o[6] = f2bf(b.z); o[7] = f2bf(b.w);
    *(u16x8*)((u16*)(ws + WS_XBF) + (size_t)row * 512 + lane * 8) = o;
    float s = a.x + a.y + a.z + a.w + b.x + b.y + b.z + b.w;
    float ss = a.x * a.x + a.y * a.y + a.z * a.z + a.w * a.w +
               b.x * b.x + b.y * b.y + b.z * b.z + b.w * b.w;
    s = wsum(s); ss = wsum(ss);
    if (lane == 0) {
        float mu = s * (1.f / 512.f);
        float var = ss * (1.f / 512.f) - mu * mu;
        ws[WS_LNST + (size_t)row * 2] = mu;
        ws[WS_LNST + (size_t)row * 2 + 1] = rsqrtf(var + 1e-5f);
    }
}

// ---------------- prep: transposed (scaled) bf16 weights ----------------
// Tb[j][k] = (SCALE ? g[k] : 1) * W[k][j];  SCALE also writes Tf[j][k] = W[k][j]
template <int SCALE>
__global__ __launch_bounds__(256) void k_prep_t(
    const float* __restrict__ W, const float* __restrict__ g,
    u16* __restrict__ Tb, float* __restrict__ Tf) {
    __shared__ float tile[64][65];
    int k0 = blockIdx.x * 64, j0 = blockIdx.y * 64;
    int tid = threadIdx.x;
    int c = (tid & 15) * 4, r0 = tid >> 4;
#pragma unroll
    for (int p = 0; p < 4; p++) {
        int r = r0 + p * 16;
        *(float4*)&tile[r][c] = *(const float4*)(W + (size_t)(k0 + r) * 512 + j0 + c);
    }
    __syncthreads();
    int kc = (tid & 15) * 4, jr0 = tid >> 4;
#pragma unroll
    for (int p = 0; p < 4; p++) {
        int jr = jr0 + p * 16;
        float v0 = tile[kc + 0][jr], v1 = tile[kc + 1][jr];
        float v2 = tile[kc + 2][jr], v3 = tile[kc + 3][jr];
        if (SCALE) {
            *(float4*)(Tf + (size_t)(j0 + jr) * 512 + k0 + kc) = (float4){v0, v1, v2, v3};
            v0 *= g[k0 + kc + 0]; v1 *= g[k0 + kc + 1];
            v2 *= g[k0 + kc + 2]; v3 *= g[k0 + kc + 3];
        }
        u16x4 ob = {f2bf(v0), f2bf(v1), f2bf(v2), f2bf(v3)};
        *(u16x4*)(Tb + (size_t)(j0 + jr) * 512 + k0 + kc) = ob;
    }
}

// ---------------- prep2: u = g@W, cb = b@W (from WT f32) ----------------
__global__ __launch_bounds__(256) void k_prep_u(
    const float* __restrict__ g, const float* __restrict__ b, float* __restrict__ ws) {
    int wid = threadIdx.x >> 6, lane = threadIdx.x & 63;
    int j = blockIdx.x * 4 + wid;              // 0..511
    const float* Tf = ws + WS_WTF32 + (size_t)j * 512;
    float su = 0.f, sc = 0.f;
#pragma unroll
    for (int m = 0; m < 8; m++) {
        int k = lane * 8 + m;
        float w = Tf[k];
        su += g[k] * w; sc += b[k] * w;
    }
    su = wsum(su); sc = wsum(sc);
    if (lane == 0) { ws[WS_U + j] = su; ws[WS_CB + j] = sc; }
}

// ---------------- bf16 MFMA GEMM, 128x128 tile, BK=32, m97-style 2-phase ----
// MODE 0 (proj): A = XBF [24576][512], B = W'T; epilogue: f = rs*acc - rs*mu*u + cb,
//   scatter bf16 into FQ/FK/FV + fused row stats (invn, mean) + col partials (COLP)
// MODE 1 (out): A = OATT bf16, B = w_outT; epilogue: +bias, f32 row-major
template <int MODE>
__global__ __launch_bounds__(256) void k_gemm(
    const u16* __restrict__ A, const u16* __restrict__ B,
    float* __restrict__ ws, float* __restrict__ out, const float* __restrict__ bias) {
    __shared__ char smem[32768];               // 2 bufs x (A 8K + B 8K)
    __shared__ float colred[2][2][64][2];
    int tid = threadIdx.x;
    int wid = tid >> 6, lane = tid & 63;
    int i15 = lane & 15, q4 = lane >> 4;
    int wm = wid >> 1, wn = wid & 1;
    int m0 = blockIdx.y * 128, c0 = blockIdx.x * 128;

    floatx4 acc[4][4];
#pragma unroll
    for (int i = 0; i < 4; i++)
#pragma unroll
        for (int j = 0; j < 4; j++) acc[i][j] = (floatx4){0.f, 0.f, 0.f, 0.f};

    const u16* gA = A + (size_t)m0 * 512;
    const u16* gB = B + (size_t)c0 * 512;

    auto stage = [&](int buf, int ks) {
#pragma unroll
        for (int e = 0; e < 4; e++) {
            int o = (e & 1) * 4096 + wid * 1024 + lane * 16;   // byte off in region
            int srow = o >> 6, s = (o >> 4) & 3;
            int cch = (s - (srow >> 1)) & 3;                   // inverse rotation
            const u16* g = ((e < 2) ? gA : gB) + (size_t)srow * 512 + ks * 32 + cch * 8;
            char* l = smem + buf * 16384 + (e < 2 ? 0 : 8192) + (e & 1) * 4096 + wid * 1024;
            __builtin_amdgcn_global_load_lds(
                (const __attribute__((address_space(1))) void*)g,
                (__attribute__((address_space(3))) void*)l, 16, 0, 0);
        }
    };

    stage(0, 0);
    __syncthreads();
    for (int ks = 0; ks < 16; ks++) {
        int buf = ks & 1;
        if (ks < 15) stage(buf ^ 1, ks + 1);
        short8 a[4], b[4];
#pragma unroll
        for (int f = 0; f < 4; f++) {
            int ra = wm * 64 + f * 16 + i15;
            int sa = (q4 + (ra >> 1)) & 3;                     // rotation swizzle
            a[f] = *(const short8*)(smem + buf * 16384 + ra * 64 + sa * 16);
            int rb = wn * 64 + f * 16 + i15;
            int sb = (q4 + (rb >> 1)) & 3;
            b[f] = *(const short8*)(smem + buf * 16384 + 8192 + rb * 64 + sb * 16);
        }
#pragma unroll
        for (int fm = 0; fm < 4; fm++)
#pragma unroll
            for (int fn = 0; fn < 4; fn++)
                acc[fm][fn] = __builtin_amdgcn_mfma_f32_16x16x32_bf16(
                    a[fm], b[fn], acc[fm][fn], 0, 0, 0);
        __syncthreads();
    }

    if constexpr (MODE == 1) {
#pragma unroll
        for (int fm = 0; fm < 4; fm++)
#pragma unroll
            for (int reg = 0; reg < 4; reg++) {
                int gm = m0 + wm * 64 + fm * 16 + q4 * 4 + reg;
#pragma unroll
                for (int fn = 0; fn < 4; fn++) {
                    int gc = c0 + wn * 64 + fn * 16 + i15;
                    out[(size_t)gm * 512 + gc] = acc[fm][fn][reg] + bias[gc];
                }
            }
    } else {
        int t = m0 >> 13;
        int rr = m0 & 8191, qg = rr >> 10, nblk = (rr >> 7) & 7;
        int h = (c0 >> 6) + wn, hq = h * 8 + qg;
        u16* fout = (u16*)(ws + (t == 0 ? WS_FQ : t == 1 ? WS_FK : WS_FV));
        float u_[4], cb_[4];
#pragma unroll
        for (int fn = 0; fn < 4; fn++) {
            int gc = c0 + wn * 64 + fn * 16 + i15;
            u_[fn] = ws[WS_U + gc]; cb_[fn] = ws[WS_CB + gc];
        }
        float rsum[4][4], rss[4][4];
        float csum[4] = {0, 0, 0, 0}, css[4] = {0, 0, 0, 0};
#pragma unroll
        for (int fm = 0; fm < 4; fm++) {
#pragma unroll
            for (int reg = 0; reg < 4; reg++) {
                int gm = m0 + wm * 64 + fm * 16 + q4 * 4 + reg;
                float2 st = *(const float2*)(ws + WS_LNST + (size_t)gm * 2);
                float mu = st.x, rs = st.y;
                int n = gm & 1023;
                float r1 = 0.f, r2 = 0.f;
#pragma unroll
                for (int fn = 0; fn < 4; fn++) {
                    float val = rs * acc[fm][fn][reg] - rs * mu * u_[fn] + cb_[fn];
                    fout[(size_t)hq * 65536 + n * 64 + fn * 16 + i15] = f2bf(val);
                    r1 += val; r2 += val * val;
                    csum[fn] += val; css[fn] += val * val;
                }
                rsum[fm][reg] = r1; rss[fm][reg] = r2;
            }
        }
        if (t < 2) {
            float* invn = ws + (t ? WS_INVNK : WS_INVNQ) + (size_t)hq * 1024;
            float* mean = ws + (t ? WS_KMEAN : WS_QMEAN) + (size_t)hq * 1024;
#pragma unroll
            for (int fm = 0; fm < 4; fm++)
#pragma unroll
                for (int reg = 0; reg < 4; reg++) {
                    float s1 = rsum[fm][reg], s2 = rss[fm][reg];
#pragma unroll
                    for (int m = 1; m < 16; m <<= 1) {
                        s1 += __shfl_xor(s1, m, 64);
                        s2 += __shfl_xor(s2, m, 64);
                    }
                    if (i15 == fm * 4 + reg) {
                        int n = (m0 & 1023) + wm * 64 + fm * 16 + q4 * 4 + reg;
                        invn[n] = rsqrtf(s2);
                        mean[n] = s1 * (1.f / 64.f);
                    }
                }
#pragma unroll
            for (int fn = 0; fn < 4; fn++) {
                float s1 = csum[fn], s2 = css[fn];
                s1 += __shfl_xor(s1, 16, 64); s1 += __shfl_xor(s1, 32, 64);
                s2 += __shfl_xor(s2, 16, 64); s2 += __shfl_xor(s2, 32, 64);
                if (q4 == fn) {
                    colred[wm][wn][fn * 16 + i15][0] = s1;
                    colred[wm][wn][fn * 16 + i15][1] = s2;
                }
            }
        }
        __syncthreads();
        if (t < 2 && wm == 0) {
            float s1 = colred[0][wn][lane][0] + colred[1][wn][lane][0];
            float s2 = colred[0][wn][lane][1] + colred[1][wn][lane][1];
            *(float2*)(ws + WS_COLP + (size_t)(((t * 64 + hq) * 8 + nblk) * 64 + lane) * 2) =
                (float2){s1, s2};
        }
    }
}

// ---------------- K3: gate MLP + variance penalty (1 wave) ----------------
__global__ __launch_bounds__(64) void k_gate(
    const float* __restrict__ pw1, const float* __restrict__ pb1,
    const float* __restrict__ plg, const float* __restrict__ plb,
    const float* __restrict__ pw2, const float* __restrict__ pb2,
    float* __restrict__ ws) {
    int lane = threadIdx.x;
    float Sq = 0, SSq = 0, Sk = 0, SSk = 0;
    for (int i = 0; i < 512; i++) {
        float2 aq = *(const float2*)(ws + WS_COLP + (size_t)i * 128 + lane * 2);
        float2 ak = *(const float2*)(ws + WS_COLP + 65536 + (size_t)i * 128 + lane * 2);
        Sq += aq.x; SSq += aq.y; Sk += ak.x; SSk += ak.y;
    }
    const float NR = 65536.f;
    float stdq = sqrtf((SSq - Sq * Sq / NR) / (NR - 1.f) + 1e-4f);
    float stdk = sqrtf((SSk - Sk * Sk / NR) / (NR - 1.f) + 1e-4f);
    float vpen = (wsum(fmaxf(1.f - stdq, 0.f)) + wsum(fmaxf(1.f - stdk, 0.f))) * (1.f / 64.f);

    __shared__ float xg[8][128];
    __shared__ float w1[128][64];
    for (int h = 0; h < 8; h++) {
        float sq = 0, sk = 0;
        for (int i = h * 64; i < h * 64 + 64; i++) {
            sq += ws[WS_COLP + (size_t)i * 128 + lane * 2];
            sk += ws[WS_COLP + 65536 + (size_t)i * 128 + lane * 2];
        }
        xg[h][lane] = sq * (1.f / 8192.f);
        xg[h][64 + lane] = sk * (1.f / 8192.f);
    }
    for (int i = 0; i < 128; i++) w1[i][lane] = pw1[i * 64 + lane];
    __syncthreads();
    float gammav = plg[lane], betav = plb[lane], w2v = pw2[lane];
    for (int h = 0; h < 8; h++) {
        float y = pb1[lane];
        for (int i = 0; i < 128; i++) y = fmaf(xg[h][i], w1[i][lane], y);
        float mu = wsum(y) * (1.f / 64.f);
        float dv = y - mu;
        float var = wsum(dv * dv) * (1.f / 64.f);
        float z = dv * rsqrtf(var + 1e-5f) * gammav + betav;
        float r = fmaxf(z, 0.f);
        float sdot = wsum(r * w2v);
        if (lane == 0) {
            float wv = 1.f / (1.f + expf(-(sdot + pb2[0])));
            ws[WS_WGATE + h] = wv / (1.f + vpen);
        }
    }
}

// ---------------- K4: build M,C (64x64 per hq), split-K over 4 parts -------
__global__ __launch_bounds__(256) void k_mc(float* __restrict__ ws) {
    int part = blockIdx.x, hq = blockIdx.y;
    const u16* fk = (const u16*)(ws + WS_FK) + (size_t)hq * 65536;
    const u16* fv = (const u16*)(ws + WS_FV) + (size_t)hq * 65536;
    const float* invk = ws + WS_INVNK + (size_t)hq * 1024;
    const float* kmg = ws + WS_KMEAN + (size_t)hq * 1024;
    __shared__ float fks[64][68], fkc[64][68], fvs[64][68];
    int tid = threadIdx.x;
    int e2 = (tid & 31) * 2, d0 = (tid >> 5) * 8;
    float am[2][8], ac[2][8];
#pragma unroll
    for (int r = 0; r < 2; r++)
#pragma unroll
        for (int j = 0; j < 8; j++) { am[r][j] = 0.f; ac[r][j] = 0.f; }

    for (int ch = 0; ch < 4; ch++) {
        int m0 = part * 256 + ch * 64;
        {
            int mr = tid >> 2, cq = (tid & 3) * 16;
            float inv = invk[m0 + mr], km = kmg[m0 + mr];
            const u16* fkr = fk + (size_t)(m0 + mr) * 64 + cq;
            const u16* fvr = fv + (size_t)(m0 + mr) * 64 + cq;
            u16x8 k0v = *(const u16x8*)fkr, k1v = *(const u16x8*)(fkr + 8);
            u16x8 v0v = *(const u16x8*)fvr, v1v = *(const u16x8*)(fvr + 8);
#pragma unroll
            for (int j = 0; j < 8; j++) {
                float kf = bf2f(k0v[j]);
                fks[mr][cq + j] = kf * inv; fkc[mr][cq + j] = kf - km;
                fvs[mr][cq + j] = bf2f(v0v[j]);
                kf = bf2f(k1v[j]);
                fks[mr][cq + 8 + j] = kf * inv; fkc[mr][cq + 8 + j] = kf - km;
                fvs[mr][cq + 8 + j] = bf2f(v1v[j]);
            }
        }
        __syncthreads();
#pragma unroll 4
        for (int mm = 0; mm < 64; mm++) {
            float2 as = *(float2*)&fks[mm][e2];
            float2 av = *(float2*)&fkc[mm][e2];
            float b[8];
            *(float4*)(b) = *(float4*)&fvs[mm][d0];
            *(float4*)(b + 4) = *(float4*)&fvs[mm][d0 + 4];
#pragma unroll
            for (int j = 0; j < 8; j++) {
                am[0][j] = fmaf(as.x, b[j], am[0][j]);
                am[1][j] = fmaf(as.y, b[j], am[1][j]);
                ac[0][j] = fmaf(av.x, b[j], ac[0][j]);
                ac[1][j] = fmaf(av.y, b[j], ac[1][j]);
            }
        }
        __syncthreads();
    }
    float* pm = ws + WS_MCP + ((size_t)(0 * 4 + part) * 64 + hq) * 4096;
    float* pc = ws + WS_MCP + ((size_t)(1 * 4 + part) * 64 + hq) * 4096;
#pragma unroll
    for (int r = 0; r < 2; r++) {
        *(float4*)(pm + (e2 + r) * 64 + d0) = *(float4*)&am[r][0];
        *(float4*)(pm + (e2 + r) * 64 + d0 + 4) = *(float4*)&am[r][4];
        *(float4*)(pc + (e2 + r) * 64 + d0) = *(float4*)&ac[r][0];
        *(float4*)(pc + (e2 + r) * 64 + d0 + 4) = *(float4*)&ac[r][4];
    }
}

// ---------------- K4b: reduce split-K partials ----------------
__global__ __launch_bounds__(256) void k_mcred(float* __restrict__ ws) {
    int cell = blockIdx.x * 256 + threadIdx.x;   // < 524288
    int mat = cell >> 18, rem = cell & 262143;
    float s = 0.f;
#pragma unroll
    for (int p = 0; p < 4; p++) s += ws[WS_MCP + (size_t)(mat * 4 + p) * 262144 + rem];
    ws[WS_MBUF + (size_t)mat * 262144 + rem] = s;
}

// ---- K5: out_attn = (1-w)/nq * fq@M + (w/64)*(fq-qmean)@C  (bf16 out) ----
__global__ __launch_bounds__(256) void k_apply(float* __restrict__ ws) {
    int nt = blockIdx.x, hq = blockIdx.y;
    int h = hq >> 3, qg = hq & 7;
    __shared__ float Ms[64][68], Cs[64][68];
    int tid = threadIdx.x;
#pragma unroll
    for (int i = 0; i < 4; i++) {
        int idx = tid + 256 * i;
        int e = idx >> 4, d4 = (idx & 15) * 4;
        *(float4*)&Ms[e][d4] = *(const float4*)(ws + WS_MBUF + (size_t)hq * 4096 + e * 64 + d4);
        *(float4*)&Cs[e][d4] = *(const float4*)(ws + WS_CBUF + (size_t)hq * 4096 + e * 64 + d4);
    }
    float w = ws[WS_WGATE + h];
    float c1 = 1.f - w, c2 = w * (1.f / 64.f);
    __syncthreads();
    int wid = tid >> 6, lane = tid & 63;
    float colC = 0.f;
#pragma unroll 16
    for (int e = 0; e < 64; e++) colC += Cs[e][lane];

    const u16* fq = (const u16*)(ws + WS_FQ) + (size_t)hq * 65536;
    const float* qm = ws + WS_QMEAN + (size_t)hq * 1024;
    const float* inv = ws + WS_INVNQ + (size_t)hq * 1024;
    u16* oat = (u16*)(ws + WS_OATT);
    int nb = nt * 128 + wid * 32;
    for (int g = 0; g < 8; g++) {
        int n = nb + g * 4;
        float a0 = bf2f(fq[(size_t)(n + 0) * 64 + lane]);
        float a1 = bf2f(fq[(size_t)(n + 1) * 64 + lane]);
        float a2 = bf2f(fq[(size_t)(n + 2) * 64 + lane]);
        float a3 = bf2f(fq[(size_t)(n + 3) * 64 + lane]);
        float m0a = 0, m1a = 0, m2a = 0, m3a = 0;
        float c0a = 0, c1a = 0, c2a = 0, c3a = 0;
#pragma unroll 16
        for (int e = 0; e < 64; e++) {
            float mv = Ms[e][lane], cv = Cs[e][lane];
            float b0 = rdlane(a0, e), b1 = rdlane(a1, e);
            float b2 = rdlane(a2, e), b3 = rdlane(a3, e);
            m0a = fmaf(b0, mv, m0a); m1a = fmaf(b1, mv, m1a);
            m2a = fmaf(b2, mv, m2a); m3a = fmaf(b3, mv, m3a);
            c0a = fmaf(b0, cv, c0a); c1a = fmaf(b1, cv, c1a);
            c2a = fmaf(b2, cv, c2a); c3a = fmaf(b3, cv, c3a);
        }
#pragma unroll
        for (int r = 0; r < 4; r++) {
            float ma = (r == 0) ? m0a : (r == 1) ? m1a : (r == 2) ? m2a : m3a;
            float ca = (r == 0) ? c0a : (r == 1) ? c1a : (r == 2) ? c2a : c3a;
            float qmv = qm[n + r], invv = inv[n + r];
            float val = c1 * invv * ma + c2 * (ca - qmv * colC);
            oat[((size_t)qg * 1024 + n + r) * 512 + h * 64 + lane] = f2bf(val);
        }
    }
}

// ---------------- host launch ----------------
extern "C" void kernel_launch(void* const* d_in, const int* in_sizes, int n_in,
                              void* d_out, int out_size, void* d_ws, size_t ws_size,
                              hipStream_t stream) {
    (void)in_sizes; (void)n_in; (void)out_size; (void)ws_size;
    const float* q = (const float*)d_in[0];
    const float* k = (const float*)d_in[1];
    const float* v = (const float*)d_in[2];
    const float* ln_g = (const float*)d_in[3];
    const float* ln_b = (const float*)d_in[4];
    const float* w_in = (const float*)d_in[5];
    const float* p_w1 = (const float*)d_in[6];
    const float* p_b1 = (const float*)d_in[7];
    const float* p_ln_g = (const float*)d_in[8];
    const float* p_ln_b = (const float*)d_in[9];
    const float* p_w2 = (const float*)d_in[10];
    const float* p_b2 = (const float*)d_in[11];
    const float* w_out = (const float*)d_in[12];
    const float* b_out = (const float*)d_in[13];
    float* ws = (float*)d_ws;
    float* out = (float*)d_out;

    k_lnstats<<<6144, 256, 0, stream>>>(q, k, v, ws);
    k_prep_t<1><<<dim3(8, 8), 256, 0, stream>>>(w_in, ln_g, (u16*)(ws + WS_WPT), ws + WS_WTF32);
    k_prep_t<0><<<dim3(8, 8), 256, 0, stream>>>(w_out, nullptr, (u16*)(ws + WS_WOT), nullptr);
    k_prep_u<<<128, 256, 0, stream>>>(ln_g, ln_b, ws);
    k_gemm<0><<<dim3(4, 192), 256, 0, stream>>>((const u16*)(ws + WS_XBF),
                                                (const u16*)(ws + WS_WPT), ws, nullptr, nullptr);
    k_gate<<<1, 64, 0, stream>>>(p_w1, p_b1, p_ln_g, p_ln_b, p_w2, p_b2, ws);
    k_mc<<<dim3(4, 64), 256, 0, stream>>>(ws);
    k_mcred<<<2048, 256, 0, stream>>>(ws);
    k_apply<<<dim3(8, 64), 256, 0, stream>>>(ws);
    k_gemm<1><<<dim3(4, 64), 256, 0, stream>>>((const u16*)(ws + WS_OATT),
                                               (const u16*)(ws + WS_WOT), ws, out, b_out);
}

// Round 3
// 185.503 us; speedup vs baseline: 3.3300x; 1.0386x over previous
//
#include <hip/hip_runtime.h>
#include <cstdint>

// ---------------- problem constants ----------------
// QG=8, N=1024, DIM=512, H=8, D=64; rows/tensor=8192; HQ=64
// f layout: [hq][n][d] (bf16), idx = hq*65536 + n*64 + d

typedef unsigned short u16;
typedef unsigned int u32;
typedef __attribute__((ext_vector_type(8))) unsigned short u16x8;
typedef __attribute__((ext_vector_type(4))) unsigned short u16x4;
typedef __attribute__((ext_vector_type(8))) short short8;
typedef __attribute__((ext_vector_type(4))) float floatx4;

// ---------------- workspace layout (float offsets) ----------------
#define WS_XBF     0LL          // bf16 [24576][512]  (q,k,v stacked)
#define WS_MCP     0LL          // f32 [2][8][64][4096]  (aliases XBF, used after)
#define WS_OATT    4194304LL    // bf16 [8192][512]      (aliases XBF tail, after MCP dead)
#define WS_WPT     6291456LL    // bf16 W'T [512][512]
#define WS_WOT     6422528LL    // bf16 w_outT [512][512]
#define WS_U       6553600LL    // f32 [512]  g@W_in
#define WS_CB      6554112LL    // f32 [512]  b@W_in
#define WS_LNST    6554624LL    // f32 [24576][2] (mu, rsigma)
#define WS_FQ      6603776LL    // bf16 [64][1024][64]
#define WS_FK      8700928LL
#define WS_FV      10798080LL
#define WS_INVNQ   12895232LL   // f32 [64][1024]
#define WS_INVNK   12960768LL
#define WS_QMEAN   13026304LL
#define WS_KMEAN   13091840LL
#define WS_COLP    13157376LL   // f32 [2][64][8][64][2] (sum, sumsq)
#define WS_WGATE   13288448LL   // f32 [8] (+pad)
#define WS_MBUF    13288512LL   // f32 [64][64][64]
#define WS_WTF32   13288512LL   // f32 WT [512][512] (aliases MBUF, prep-phase only)
#define WS_CBUF    13550656LL   // f32 [64][64][64]   (end = 13812800 fl = 55.3 MB)

__device__ __forceinline__ float wsum(float v) {
#pragma unroll
    for (int m = 32; m; m >>= 1) v += __shfl_xor(v, m, 64);
    return v;
}
__device__ __forceinline__ float rdlane(float v, int l) {
    return __int_as_float(__builtin_amdgcn_readlane(__float_as_int(v), l));
}
__device__ __forceinline__ u16 f2bf(float f) {
    u32 u = __float_as_uint(f);
    u32 r = u + 0x7fffu + ((u >> 16) & 1u);
    return (u16)(r >> 16);
}
__device__ __forceinline__ float bf2f(u16 u) {
    return __uint_as_float(((u32)u) << 16);
}

// ---------------- K0: LN row stats over DIM=512 + bf16 copy ----------------
__global__ __launch_bounds__(256) void k_lnstats(
    const float* __restrict__ q, const float* __restrict__ k,
    const float* __restrict__ v, float* __restrict__ ws) {
    int wid = threadIdx.x >> 6, lane = threadIdx.x & 63;
    int row = blockIdx.x * 4 + wid;            // 0..24575
    int t = row >> 13, r = row & 8191;
    const float* src = (t == 0) ? q : ((t == 1) ? k : v);
    const float4* p = (const float4*)(src + (size_t)r * 512) + lane * 2;
    float4 a = p[0], b = p[1];
    u16x8 o;
    o[0] = f2bf(a.x); o[1] = f2bf(a.y); o[2] = f2bf(a.z); o[3] = f2bf(a.w);
    o[4] = f2bf(b.x); o[5] = f2bf(b.y); o[6] = f2bf(b.z); o[7] = f2bf(b.w);
    *(u16x8*)((u16*)(ws + WS_XBF) + (size_t)row * 512 + lane * 8) = o;
    float s = a.x + a.y + a.z + a.w + b.x + b.y + b.z + b.w;
    float ss = a.x * a.x + a.y * a.y + a.z * a.z + a.w * a.w +
               b.x * b.x + b.y * b.y + b.z * b.z + b.w * b.w;
    s = wsum(s); ss = wsum(ss);
    if (lane == 0) {
        float mu = s * (1.f / 512.f);
        float var = ss * (1.f / 512.f) - mu * mu;
        ws[WS_LNST + (size_t)row * 2] = mu;
        ws[WS_LNST + (size_t)row * 2 + 1] = rsqrtf(var + 1e-5f);
    }
}

// ---------------- prep: transposed (scaled) bf16 weights ----------------
template <int SCALE>
__global__ __launch_bounds__(256) void k_prep_t(
    const float* __restrict__ W, const float* __restrict__ g,
    u16* __restrict__ Tb, float* __restrict__ Tf) {
    __shared__ float tile[64][65];
    int k0 = blockIdx.x * 64, j0 = blockIdx.y * 64;
    int tid = threadIdx.x;
    int c = (tid & 15) * 4, r0 = tid >> 4;
#pragma unroll
    for (int p = 0; p < 4; p++) {
        int r = r0 + p * 16;
        *(float4*)&tile[r][c] = *(const float4*)(W + (size_t)(k0 + r) * 512 + j0 + c);
    }
    __syncthreads();
    int kc = (tid & 15) * 4, jr0 = tid >> 4;
#pragma unroll
    for (int p = 0; p < 4; p++) {
        int jr = jr0 + p * 16;
        float v0 = tile[kc + 0][jr], v1 = tile[kc + 1][jr];
        float v2 = tile[kc + 2][jr], v3 = tile[kc + 3][jr];
        if (SCALE) {
            *(float4*)(Tf + (size_t)(j0 + jr) * 512 + k0 + kc) = (float4){v0, v1, v2, v3};
            v0 *= g[k0 + kc + 0]; v1 *= g[k0 + kc + 1];
            v2 *= g[k0 + kc + 2]; v3 *= g[k0 + kc + 3];
        }
        u16x4 ob = {f2bf(v0), f2bf(v1), f2bf(v2), f2bf(v3)};
        *(u16x4*)(Tb + (size_t)(j0 + jr) * 512 + k0 + kc) = ob;
    }
}

// ---------------- prep2: u = g@W, cb = b@W (from WT f32) ----------------
__global__ __launch_bounds__(256) void k_prep_u(
    const float* __restrict__ g, const float* __restrict__ b, float* __restrict__ ws) {
    int wid = threadIdx.x >> 6, lane = threadIdx.x & 63;
    int j = blockIdx.x * 4 + wid;              // 0..511
    const float* Tf = ws + WS_WTF32 + (size_t)j * 512;
    float su = 0.f, sc = 0.f;
#pragma unroll
    for (int m = 0; m < 8; m++) {
        int k = lane * 8 + m;
        float w = Tf[k];
        su += g[k] * w; sc += b[k] * w;
    }
    su = wsum(su); sc = wsum(sc);
    if (lane == 0) { ws[WS_U + j] = su; ws[WS_CB + j] = sc; }
}

// ---------------- bf16 MFMA GEMM, 128x128 tile, BK=32 ----------------------
// 3-stage LDS pipeline, counted vmcnt (T3/T4), XCD-bijective swizzle (T1).
// MODE 0 (proj): epilogue f = rs*acc - rs*mu*u + cb, bf16 scatter + fused stats
// MODE 1 (out): +bias, f32 row-major.  CPX = gridblocks/8 (per-XCD chunk).
template <int MODE, int CPX>
__global__ __launch_bounds__(256) void k_gemm(
    const u16* __restrict__ A, const u16* __restrict__ B,
    float* __restrict__ ws, float* __restrict__ out, const float* __restrict__ bias) {
    __shared__ char smem[49152];               // 3 bufs x (A 8K + B 8K)
    __shared__ float colred[2][2][64][2];
    int tid = threadIdx.x;
    int wid = tid >> 6, lane = tid & 63;
    int i15 = lane & 15, q4 = lane >> 4;
    int wm = wid >> 1, wn = wid & 1;
    // XCD-bijective swizzle: consecutive logical blocks (same A row panel) on one XCD
    int flat = blockIdx.x + (blockIdx.y << 2);
    int swz = (flat & 7) * CPX + (flat >> 3);
    int c0 = (swz & 3) * 128, m0 = (swz >> 2) * 128;

    floatx4 acc[4][4];
#pragma unroll
    for (int i = 0; i < 4; i++)
#pragma unroll
        for (int j = 0; j < 4; j++) acc[i][j] = (floatx4){0.f, 0.f, 0.f, 0.f};

    const u16* gA = A + (size_t)m0 * 512;
    const u16* gB = B + (size_t)c0 * 512;

    auto stage = [&](int ks, int buf) {
#pragma unroll
        for (int e = 0; e < 4; e++) {
            int o = (e & 1) * 4096 + wid * 1024 + lane * 16;   // byte off in region
            int srow = o >> 6, s = (o >> 4) & 3;
            int cch = (s - (srow >> 1)) & 3;                   // inverse rotation
            const u16* g = ((e < 2) ? gA : gB) + (size_t)srow * 512 + ks * 32 + cch * 8;
            char* l = smem + buf * 16384 + (e < 2 ? 0 : 8192) + (e & 1) * 4096 + wid * 1024;
            __builtin_amdgcn_global_load_lds(
                (const __attribute__((address_space(1))) void*)g,
                (__attribute__((address_space(3))) void*)l, 16, 0, 0);
        }
    };

    stage(0, 0);
    stage(1, 1);
    for (int ks = 0; ks < 16; ks++) {
        __builtin_amdgcn_sched_barrier(0);
        if (ks < 15) asm volatile("s_waitcnt vmcnt(4)" ::: "memory");
        else         asm volatile("s_waitcnt vmcnt(0)" ::: "memory");
        __builtin_amdgcn_s_barrier();
        __builtin_amdgcn_sched_barrier(0);
        if (ks + 2 < 16) stage(ks + 2, (ks + 2) % 3);
        int buf = ks % 3;
        short8 a[4], b[4];
#pragma unroll
        for (int f = 0; f < 4; f++) {
            int ra = wm * 64 + f * 16 + i15;
            int sa = (q4 + (ra >> 1)) & 3;                     // rotation swizzle
            a[f] = *(const short8*)(smem + buf * 16384 + ra * 64 + sa * 16);
            int rb = wn * 64 + f * 16 + i15;
            int sb = (q4 + (rb >> 1)) & 3;
            b[f] = *(const short8*)(smem + buf * 16384 + 8192 + rb * 64 + sb * 16);
        }
#pragma unroll
        for (int fm = 0; fm < 4; fm++)
#pragma unroll
            for (int fn = 0; fn < 4; fn++)
                acc[fm][fn] = __builtin_amdgcn_mfma_f32_16x16x32_bf16(
                    a[fm], b[fn], acc[fm][fn], 0, 0, 0);
    }

    if constexpr (MODE == 1) {
#pragma unroll
        for (int fm = 0; fm < 4; fm++)
#pragma unroll
            for (int reg = 0; reg < 4; reg++) {
                int gm = m0 + wm * 64 + fm * 16 + q4 * 4 + reg;
#pragma unroll
                for (int fn = 0; fn < 4; fn++) {
                    int gc = c0 + wn * 64 + fn * 16 + i15;
                    out[(size_t)gm * 512 + gc] = acc[fm][fn][reg] + bias[gc];
                }
            }
    } else {
        int t = m0 >> 13;
        int rr = m0 & 8191, qg = rr >> 10, nblk = (rr >> 7) & 7;
        int h = (c0 >> 6) + wn, hq = h * 8 + qg;
        u16* fout = (u16*)(ws + (t == 0 ? WS_FQ : t == 1 ? WS_FK : WS_FV));
        float u_[4], cb_[4];
#pragma unroll
        for (int fn = 0; fn < 4; fn++) {
            int gc = c0 + wn * 64 + fn * 16 + i15;
            u_[fn] = ws[WS_U + gc]; cb_[fn] = ws[WS_CB + gc];
        }
        float rsum[4][4], rss[4][4];
        float csum[4] = {0, 0, 0, 0}, css[4] = {0, 0, 0, 0};
#pragma unroll
        for (int fm = 0; fm < 4; fm++) {
#pragma unroll
            for (int reg = 0; reg < 4; reg++) {
                int gm = m0 + wm * 64 + fm * 16 + q4 * 4 + reg;
                float2 st = *(const float2*)(ws + WS_LNST + (size_t)gm * 2);
                float mu = st.x, rs = st.y;
                int n = gm & 1023;
                float r1 = 0.f, r2 = 0.f;
#pragma unroll
                for (int fn = 0; fn < 4; fn++) {
                    float val = rs * acc[fm][fn][reg] - rs * mu * u_[fn] + cb_[fn];
                    fout[(size_t)hq * 65536 + n * 64 + fn * 16 + i15] = f2bf(val);
                    r1 += val; r2 += val * val;
                    csum[fn] += val; css[fn] += val * val;
                }
                rsum[fm][reg] = r1; rss[fm][reg] = r2;
            }
        }
        if (t < 2) {
            float* invn = ws + (t ? WS_INVNK : WS_INVNQ) + (size_t)hq * 1024;
            float* mean = ws + (t ? WS_KMEAN : WS_QMEAN) + (size_t)hq * 1024;
#pragma unroll
            for (int fm = 0; fm < 4; fm++)
#pragma unroll
                for (int reg = 0; reg < 4; reg++) {
                    float s1 = rsum[fm][reg], s2 = rss[fm][reg];
#pragma unroll
                    for (int m = 1; m < 16; m <<= 1) {
                        s1 += __shfl_xor(s1, m, 64);
                        s2 += __shfl_xor(s2, m, 64);
                    }
                    if (i15 == fm * 4 + reg) {
                        int n = (m0 & 1023) + wm * 64 + fm * 16 + q4 * 4 + reg;
                        invn[n] = rsqrtf(s2);
                        mean[n] = s1 * (1.f / 64.f);
                    }
                }
#pragma unroll
            for (int fn = 0; fn < 4; fn++) {
                float s1 = csum[fn], s2 = css[fn];
                s1 += __shfl_xor(s1, 16, 64); s1 += __shfl_xor(s1, 32, 64);
                s2 += __shfl_xor(s2, 16, 64); s2 += __shfl_xor(s2, 32, 64);
                if (q4 == fn) {
                    colred[wm][wn][fn * 16 + i15][0] = s1;
                    colred[wm][wn][fn * 16 + i15][1] = s2;
                }
            }
        }
        __syncthreads();
        if (t < 2 && wm == 0) {
            float s1 = colred[0][wn][lane][0] + colred[1][wn][lane][0];
            float s2 = colred[0][wn][lane][1] + colred[1][wn][lane][1];
            *(float2*)(ws + WS_COLP + (size_t)(((t * 64 + hq) * 8 + nblk) * 64 + lane) * 2) =
                (float2){s1, s2};
        }
    }
}

// ---------------- K3: gate MLP + variance penalty (4 waves) ----------------
__global__ __launch_bounds__(256) void k_gate(
    const float* __restrict__ pw1, const float* __restrict__ pb1,
    const float* __restrict__ plg, const float* __restrict__ plb,
    const float* __restrict__ pw2, const float* __restrict__ pb2,
    float* __restrict__ ws) {
    int tid = threadIdx.x, wid = tid >> 6, lane = tid & 63;
    __shared__ float part[4][64][4];
    __shared__ float xg[8][128];
    __shared__ float w1[128][64];
    float Sq = 0, SSq = 0, Sk = 0, SSk = 0;
    for (int i = wid; i < 512; i += 4) {
        float2 aq = *(const float2*)(ws + WS_COLP + (size_t)i * 128 + lane * 2);
        float2 ak = *(const float2*)(ws + WS_COLP + 65536 + (size_t)i * 128 + lane * 2);
        Sq += aq.x; SSq += aq.y; Sk += ak.x; SSk += ak.y;
    }
    part[wid][lane][0] = Sq; part[wid][lane][1] = SSq;
    part[wid][lane][2] = Sk; part[wid][lane][3] = SSk;
    for (int r = wid; r < 128; r += 4) w1[r][lane] = pw1[r * 64 + lane];
#pragma unroll
    for (int hh = 0; hh < 2; hh++) {
        int h = wid * 2 + hh;
        float sq = 0, sk = 0;
        for (int i = h * 64; i < h * 64 + 64; i++) {
            sq += ws[WS_COLP + (size_t)i * 128 + lane * 2];
            sk += ws[WS_COLP + 65536 + (size_t)i * 128 + lane * 2];
        }
        xg[h][lane] = sq * (1.f / 8192.f);
        xg[h][64 + lane] = sk * (1.f / 8192.f);
    }
    __syncthreads();
    float Tq = part[0][lane][0] + part[1][lane][0] + part[2][lane][0] + part[3][lane][0];
    float TSq = part[0][lane][1] + part[1][lane][1] + part[2][lane][1] + part[3][lane][1];
    float Tk = part[0][lane][2] + part[1][lane][2] + part[2][lane][2] + part[3][lane][2];
    float TSk = part[0][lane][3] + part[1][lane][3] + part[2][lane][3] + part[3][lane][3];
    const float NR = 65536.f;
    float stdq = sqrtf((TSq - Tq * Tq / NR) / (NR - 1.f) + 1e-4f);
    float stdk = sqrtf((TSk - Tk * Tk / NR) / (NR - 1.f) + 1e-4f);
    float vpen = (wsum(fmaxf(1.f - stdq, 0.f)) + wsum(fmaxf(1.f - stdk, 0.f))) * (1.f / 64.f);
    float gammav = plg[lane], betav = plb[lane], w2v = pw2[lane];
#pragma unroll
    for (int hh = 0; hh < 2; hh++) {
        int h = wid * 2 + hh;
        float y = pb1[lane];
        for (int i = 0; i < 128; i++) y = fmaf(xg[h][i], w1[i][lane], y);
        float mu = wsum(y) * (1.f / 64.f);
        float dv = y - mu;
        float var = wsum(dv * dv) * (1.f / 64.f);
        float z = dv * rsqrtf(var + 1e-5f) * gammav + betav;
        float r = fmaxf(z, 0.f);
        float sdot = wsum(r * w2v);
        if (lane == 0) {
            float wv = 1.f / (1.f + expf(-(sdot + pb2[0])));
            ws[WS_WGATE + h] = wv / (1.f + vpen);
        }
    }
}

// ---------------- K4: build M,C (64x64 per hq), split-K over 8 parts -------
__global__ __launch_bounds__(256) void k_mc(float* __restrict__ ws) {
    int part = blockIdx.x, hq = blockIdx.y;
    const u16* fk = (const u16*)(ws + WS_FK) + (size_t)hq * 65536;
    const u16* fv = (const u16*)(ws + WS_FV) + (size_t)hq * 65536;
    const float* invk = ws + WS_INVNK + (size_t)hq * 1024;
    const float* kmg = ws + WS_KMEAN + (size_t)hq * 1024;
    __shared__ float fks[64][68], fkc[64][68], fvs[64][68];
    int tid = threadIdx.x;
    int e2 = (tid & 31) * 2, d0 = (tid >> 5) * 8;
    float am[2][8], ac[2][8];
#pragma unroll
    for (int r = 0; r < 2; r++)
#pragma unroll
        for (int j = 0; j < 8; j++) { am[r][j] = 0.f; ac[r][j] = 0.f; }

    for (int ch = 0; ch < 2; ch++) {
        int m0 = part * 128 + ch * 64;
        {
            int mr = tid >> 2, cq = (tid & 3) * 16;
            float inv = invk[m0 + mr], km = kmg[m0 + mr];
            const u16* fkr = fk + (size_t)(m0 + mr) * 64 + cq;
            const u16* fvr = fv + (size_t)(m0 + mr) * 64 + cq;
            u16x8 k0v = *(const u16x8*)fkr, k1v = *(const u16x8*)(fkr + 8);
            u16x8 v0v = *(const u16x8*)fvr, v1v = *(const u16x8*)(fvr + 8);
#pragma unroll
            for (int j = 0; j < 8; j++) {
                float kf = bf2f(k0v[j]);
                fks[mr][cq + j] = kf * inv; fkc[mr][cq + j] = kf - km;
                fvs[mr][cq + j] = bf2f(v0v[j]);
                kf = bf2f(k1v[j]);
                fks[mr][cq + 8 + j] = kf * inv; fkc[mr][cq + 8 + j] = kf - km;
                fvs[mr][cq + 8 + j] = bf2f(v1v[j]);
            }
        }
        __syncthreads();
#pragma unroll 4
        for (int mm = 0; mm < 64; mm++) {
            float2 as = *(float2*)&fks[mm][e2];
            float2 av = *(float2*)&fkc[mm][e2];
            float b[8];
            *(float4*)(b) = *(float4*)&fvs[mm][d0];
            *(float4*)(b + 4) = *(float4*)&fvs[mm][d0 + 4];
#pragma unroll
            for (int j = 0; j < 8; j++) {
                am[0][j] = fmaf(as.x, b[j], am[0][j]);
                am[1][j] = fmaf(as.y, b[j], am[1][j]);
                ac[0][j] = fmaf(av.x, b[j], ac[0][j]);
                ac[1][j] = fmaf(av.y, b[j], ac[1][j]);
            }
        }
        __syncthreads();
    }
    float* pm = ws + WS_MCP + ((size_t)(0 * 8 + part) * 64 + hq) * 4096;
    float* pc = ws + WS_MCP + ((size_t)(1 * 8 + part) * 64 + hq) * 4096;
#pragma unroll
    for (int r = 0; r < 2; r++) {
        *(float4*)(pm + (e2 + r) * 64 + d0) = *(float4*)&am[r][0];
        *(float4*)(pm + (e2 + r) * 64 + d0 + 4) = *(float4*)&am[r][4];
        *(float4*)(pc + (e2 + r) * 64 + d0) = *(float4*)&ac[r][0];
        *(float4*)(pc + (e2 + r) * 64 + d0 + 4) = *(float4*)&ac[r][4];
    }
}

// ---------------- K4b: reduce split-K partials ----------------
__global__ __launch_bounds__(256) void k_mcred(float* __restrict__ ws) {
    int cell = blockIdx.x * 256 + threadIdx.x;   // < 524288
    int mat = cell >> 18, rem = cell & 262143;
    float s = 0.f;
#pragma unroll
    for (int p = 0; p < 8; p++) s += ws[WS_MCP + (size_t)(mat * 8 + p) * 262144 + rem];
    ws[WS_MBUF + (size_t)mat * 262144 + rem] = s;
}

// ---- K5: out_attn = (1-w)/nq * fq@M + (w/64)*(fq-qmean)@C  (bf16 out) ----
__global__ __launch_bounds__(256) void k_apply(float* __restrict__ ws) {
    int nt = blockIdx.x, hq = blockIdx.y;
    int h = hq >> 3, qg = hq & 7;
    __shared__ float Ms[64][68], Cs[64][68];
    int tid = threadIdx.x;
#pragma unroll
    for (int i = 0; i < 4; i++) {
        int idx = tid + 256 * i;
        int e = idx >> 4, d4 = (idx & 15) * 4;
        *(float4*)&Ms[e][d4] = *(const float4*)(ws + WS_MBUF + (size_t)hq * 4096 + e * 64 + d4);
        *(float4*)&Cs[e][d4] = *(const float4*)(ws + WS_CBUF + (size_t)hq * 4096 + e * 64 + d4);
    }
    float w = ws[WS_WGATE + h];
    float c1 = 1.f - w, c2 = w * (1.f / 64.f);
    __syncthreads();
    int wid = tid >> 6, lane = tid & 63;
    float colC = 0.f;
#pragma unroll 16
    for (int e = 0; e < 64; e++) colC += Cs[e][lane];

    const u16* fq = (const u16*)(ws + WS_FQ) + (size_t)hq * 65536;
    const float* qm = ws + WS_QMEAN + (size_t)hq * 1024;
    const float* inv = ws + WS_INVNQ + (size_t)hq * 1024;
    u16* oat = (u16*)(ws + WS_OATT);
    int nb = nt * 128 + wid * 32;
    for (int g = 0; g < 8; g++) {
        int n = nb + g * 4;
        float a0 = bf2f(fq[(size_t)(n + 0) * 64 + lane]);
        float a1 = bf2f(fq[(size_t)(n + 1) * 64 + lane]);
        float a2 = bf2f(fq[(size_t)(n + 2) * 64 + lane]);
        float a3 = bf2f(fq[(size_t)(n + 3) * 64 + lane]);
        float m0a = 0, m1a = 0, m2a = 0, m3a = 0;
        float c0a = 0, c1a = 0, c2a = 0, c3a = 0;
#pragma unroll 16
        for (int e = 0; e < 64; e++) {
            float mv = Ms[e][lane], cv = Cs[e][lane];
            float b0 = rdlane(a0, e), b1 = rdlane(a1, e);
            float b2 = rdlane(a2, e), b3 = rdlane(a3, e);
            m0a = fmaf(b0, mv, m0a); m1a = fmaf(b1, mv, m1a);
            m2a = fmaf(b2, mv, m2a); m3a = fmaf(b3, mv, m3a);
            c0a = fmaf(b0, cv, c0a); c1a = fmaf(b1, cv, c1a);
            c2a = fmaf(b2, cv, c2a); c3a = fmaf(b3, cv, c3a);
        }
#pragma unroll
        for (int r = 0; r < 4; r++) {
            float ma = (r == 0) ? m0a : (r == 1) ? m1a : (r == 2) ? m2a : m3a;
            float ca = (r == 0) ? c0a : (r == 1) ? c1a : (r == 2) ? c2a : c3a;
            float qmv = qm[n + r], invv = inv[n + r];
            float val = c1 * invv * ma + c2 * (ca - qmv * colC);
            oat[((size_t)qg * 1024 + n + r) * 512 + h * 64 + lane] = f2bf(val);
        }
    }
}

// ---------------- host launch ----------------
extern "C" void kernel_launch(void* const* d_in, const int* in_sizes, int n_in,
                              void* d_out, int out_size, void* d_ws, size_t ws_size,
                              hipStream_t stream) {
    (void)in_sizes; (void)n_in; (void)out_size; (void)ws_size;
    const float* q = (const float*)d_in[0];
    const float* k = (const float*)d_in[1];
    const float* v = (const float*)d_in[2];
    const float* ln_g = (const float*)d_in[3];
    const float* ln_b = (const float*)d_in[4];
    const float* w_in = (const float*)d_in[5];
    const float* p_w1 = (const float*)d_in[6];
    const float* p_b1 = (const float*)d_in[7];
    const float* p_ln_g = (const float*)d_in[8];
    const float* p_ln_b = (const float*)d_in[9];
    const float* p_w2 = (const float*)d_in[10];
    const float* p_b2 = (const float*)d_in[11];
    const float* w_out = (const float*)d_in[12];
    const float* b_out = (const float*)d_in[13];
    float* ws = (float*)d_ws;
    float* out = (float*)d_out;

    k_lnstats<<<6144, 256, 0, stream>>>(q, k, v, ws);
    k_prep_t<1><<<dim3(8, 8), 256, 0, stream>>>(w_in, ln_g, (u16*)(ws + WS_WPT), ws + WS_WTF32);
    k_prep_t<0><<<dim3(8, 8), 256, 0, stream>>>(w_out, nullptr, (u16*)(ws + WS_WOT), nullptr);
    k_prep_u<<<128, 256, 0, stream>>>(ln_g, ln_b, ws);
    k_gemm<0, 96><<<dim3(4, 192), 256, 0, stream>>>((const u16*)(ws + WS_XBF),
                                                    (const u16*)(ws + WS_WPT), ws, nullptr, nullptr);
    k_gate<<<1, 256, 0, stream>>>(p_w1, p_b1, p_ln_g, p_ln_b, p_w2, p_b2, ws);
    k_mc<<<dim3(8, 64), 256, 0, stream>>>(ws);
    k_mcred<<<2048, 256, 0, stream>>>(ws);
    k_apply<<<dim3(8, 64), 256, 0, stream>>>(ws);
    k_gemm<1, 32><<<dim3(4, 64), 256, 0, stream>>>((const u16*)(ws + WS_OATT),
                                                   (const u16*)(ws + WS_WOT), ws, out, b_out);
}

// Round 4
// 159.474 us; speedup vs baseline: 3.8735x; 1.1632x over previous
//
#include <hip/hip_runtime.h>
#include <cstdint>

// ---------------- problem constants ----------------
// QG=8, N=1024, DIM=512, H=8, D=64; rows/tensor=8192; HQ=64
// f layout: [hq][n][d] (bf16), idx = hq*65536 + n*64 + d

typedef unsigned short u16;
typedef unsigned int u32;
typedef __attribute__((ext_vector_type(8))) unsigned short u16x8;
typedef __attribute__((ext_vector_type(4))) unsigned short u16x4;
typedef __attribute__((ext_vector_type(8))) short short8;
typedef __attribute__((ext_vector_type(4))) float floatx4;

// ---------------- workspace layout (float offsets) ----------------
#define WS_XBF     0LL          // bf16 [24576][512]  (q,k,v stacked)
#define WS_MCP     0LL          // f32 [2][8][64][4096]  (aliases XBF, used after)
#define WS_OATT    4194304LL    // bf16 [8192][512]      (aliases XBF tail, after MCP dead)
#define WS_WPT     6291456LL    // bf16 W'T [512][512]
#define WS_WOT     6422528LL    // bf16 w_outT [512][512]
#define WS_U       6553600LL    // f32 [512]  g@W_in
#define WS_CB      6554112LL    // f32 [512]  b@W_in
#define WS_LNST    6554624LL    // f32 [24576][2] (mu, rsigma)
#define WS_FQ      6603776LL    // bf16 [64][1024][64]
#define WS_FK      8700928LL
#define WS_FV      10798080LL
#define WS_INVNQ   12895232LL   // f32 [64][1024]
#define WS_INVNK   12960768LL
#define WS_QMEAN   13026304LL
#define WS_KMEAN   13091840LL
#define WS_COLP    13157376LL   // f32 [2][64][8][64][2] (sum, sumsq)
#define WS_WGATE   13288448LL   // f32 [8] (+pad)
#define WS_MBUF    13288512LL   // f32 [64][64][64]
#define WS_WTF32   13288512LL   // f32 WT [512][512] (aliases MBUF, prep-phase only)
#define WS_GSUM    13288512LL   // f32 [2][8][64][2] (aliases MBUF; live gatered->gate only)
#define WS_CBUF    13550656LL   // f32 [64][64][64]   (end = 13812800 fl = 55.3 MB)

__device__ __forceinline__ float wsum(float v) {
#pragma unroll
    for (int m = 32; m; m >>= 1) v += __shfl_xor(v, m, 64);
    return v;
}
__device__ __forceinline__ float rdlane(float v, int l) {
    return __int_as_float(__builtin_amdgcn_readlane(__float_as_int(v), l));
}
__device__ __forceinline__ u16 f2bf(float f) {
    u32 u = __float_as_uint(f);
    u32 r = u + 0x7fffu + ((u >> 16) & 1u);
    return (u16)(r >> 16);
}
__device__ __forceinline__ float bf2f(u16 u) {
    return __uint_as_float(((u32)u) << 16);
}

// ---------------- K0: LN row stats over DIM=512 + bf16 copy ----------------
__global__ __launch_bounds__(256) void k_lnstats(
    const float* __restrict__ q, const float* __restrict__ k,
    const float* __restrict__ v, float* __restrict__ ws) {
    int wid = threadIdx.x >> 6, lane = threadIdx.x & 63;
    int row = blockIdx.x * 4 + wid;            // 0..24575
    int t = row >> 13, r = row & 8191;
    const float* src = (t == 0) ? q : ((t == 1) ? k : v);
    const float4* p = (const float4*)(src + (size_t)r * 512) + lane * 2;
    float4 a = p[0], b = p[1];
    u16x8 o;
    o[0] = f2bf(a.x); o[1] = f2bf(a.y); o[2] = f2bf(a.z); o[3] = f2bf(a.w);
    o[4] = f2bf(b.x); o[5] = f2bf(b.y); o[6] = f2bf(b.z); o[7] = f2bf(b.w);
    *(u16x8*)((u16*)(ws + WS_XBF) + (size_t)row * 512 + lane * 8) = o;
    float s = a.x + a.y + a.z + a.w + b.x + b.y + b.z + b.w;
    float ss = a.x * a.x + a.y * a.y + a.z * a.z + a.w * a.w +
               b.x * b.x + b.y * b.y + b.z * b.z + b.w * b.w;
    s = wsum(s); ss = wsum(ss);
    if (lane == 0) {
        float mu = s * (1.f / 512.f);
        float var = ss * (1.f / 512.f) - mu * mu;
        ws[WS_LNST + (size_t)row * 2] = mu;
        ws[WS_LNST + (size_t)row * 2 + 1] = rsqrtf(var + 1e-5f);
    }
}

// ---------------- prep: transposed (scaled) bf16 weights ----------------
template <int SCALE>
__global__ __launch_bounds__(256) void k_prep_t(
    const float* __restrict__ W, const float* __restrict__ g,
    u16* __restrict__ Tb, float* __restrict__ Tf) {
    __shared__ float tile[64][65];
    int k0 = blockIdx.x * 64, j0 = blockIdx.y * 64;
    int tid = threadIdx.x;
    int c = (tid & 15) * 4, r0 = tid >> 4;
#pragma unroll
    for (int p = 0; p < 4; p++) {
        int r = r0 + p * 16;
        *(float4*)&tile[r][c] = *(const float4*)(W + (size_t)(k0 + r) * 512 + j0 + c);
    }
    __syncthreads();
    int kc = (tid & 15) * 4, jr0 = tid >> 4;
#pragma unroll
    for (int p = 0; p < 4; p++) {
        int jr = jr0 + p * 16;
        float v0 = tile[kc + 0][jr], v1 = tile[kc + 1][jr];
        float v2 = tile[kc + 2][jr], v3 = tile[kc + 3][jr];
        if (SCALE) {
            *(float4*)(Tf + (size_t)(j0 + jr) * 512 + k0 + kc) = (float4){v0, v1, v2, v3};
            v0 *= g[k0 + kc + 0]; v1 *= g[k0 + kc + 1];
            v2 *= g[k0 + kc + 2]; v3 *= g[k0 + kc + 3];
        }
        u16x4 ob = {f2bf(v0), f2bf(v1), f2bf(v2), f2bf(v3)};
        *(u16x4*)(Tb + (size_t)(j0 + jr) * 512 + k0 + kc) = ob;
    }
}

// ---------------- prep2: u = g@W, cb = b@W (from WT f32) ----------------
__global__ __launch_bounds__(256) void k_prep_u(
    const float* __restrict__ g, const float* __restrict__ b, float* __restrict__ ws) {
    int wid = threadIdx.x >> 6, lane = threadIdx.x & 63;
    int j = blockIdx.x * 4 + wid;              // 0..511
    const float* Tf = ws + WS_WTF32 + (size_t)j * 512;
    float su = 0.f, sc = 0.f;
#pragma unroll
    for (int m = 0; m < 8; m++) {
        int k = lane * 8 + m;
        float w = Tf[k];
        su += g[k] * w; sc += b[k] * w;
    }
    su = wsum(su); sc = wsum(sc);
    if (lane == 0) { ws[WS_U + j] = su; ws[WS_CB + j] = sc; }
}

// ---------------- bf16 MFMA GEMM, 128x128 tile, BK=32 ----------------------
// 3-stage LDS pipeline, counted vmcnt (T3/T4), XCD-bijective swizzle (T1).
// MODE 0 (proj): epilogue f = rs*acc - rs*mu*u + cb, bf16 scatter + fused stats
// MODE 1 (out): +bias, f32 row-major.  CPX = gridblocks/8 (per-XCD chunk).
template <int MODE, int CPX>
__global__ __launch_bounds__(256) void k_gemm(
    const u16* __restrict__ A, const u16* __restrict__ B,
    float* __restrict__ ws, float* __restrict__ out, const float* __restrict__ bias) {
    __shared__ char smem[49152];               // 3 bufs x (A 8K + B 8K)
    __shared__ float colred[2][2][64][2];
    int tid = threadIdx.x;
    int wid = tid >> 6, lane = tid & 63;
    int i15 = lane & 15, q4 = lane >> 4;
    int wm = wid >> 1, wn = wid & 1;
    // XCD-bijective swizzle: consecutive logical blocks (same A row panel) on one XCD
    int flat = blockIdx.x + (blockIdx.y << 2);
    int swz = (flat & 7) * CPX + (flat >> 3);
    int c0 = (swz & 3) * 128, m0 = (swz >> 2) * 128;

    floatx4 acc[4][4];
#pragma unroll
    for (int i = 0; i < 4; i++)
#pragma unroll
        for (int j = 0; j < 4; j++) acc[i][j] = (floatx4){0.f, 0.f, 0.f, 0.f};

    const u16* gA = A + (size_t)m0 * 512;
    const u16* gB = B + (size_t)c0 * 512;

    auto stage = [&](int ks, int buf) {
#pragma unroll
        for (int e = 0; e < 4; e++) {
            int o = (e & 1) * 4096 + wid * 1024 + lane * 16;   // byte off in region
            int srow = o >> 6, s = (o >> 4) & 3;
            int cch = (s - (srow >> 1)) & 3;                   // inverse rotation
            const u16* g = ((e < 2) ? gA : gB) + (size_t)srow * 512 + ks * 32 + cch * 8;
            char* l = smem + buf * 16384 + (e < 2 ? 0 : 8192) + (e & 1) * 4096 + wid * 1024;
            __builtin_amdgcn_global_load_lds(
                (const __attribute__((address_space(1))) void*)g,
                (__attribute__((address_space(3))) void*)l, 16, 0, 0);
        }
    };

    stage(0, 0);
    stage(1, 1);
    for (int ks = 0; ks < 16; ks++) {
        __builtin_amdgcn_sched_barrier(0);
        if (ks < 15) asm volatile("s_waitcnt vmcnt(4)" ::: "memory");
        else         asm volatile("s_waitcnt vmcnt(0)" ::: "memory");
        __builtin_amdgcn_s_barrier();
        __builtin_amdgcn_sched_barrier(0);
        if (ks + 2 < 16) stage(ks + 2, (ks + 2) % 3);
        int buf = ks % 3;
        short8 a[4], b[4];
#pragma unroll
        for (int f = 0; f < 4; f++) {
            int ra = wm * 64 + f * 16 + i15;
            int sa = (q4 + (ra >> 1)) & 3;                     // rotation swizzle
            a[f] = *(const short8*)(smem + buf * 16384 + ra * 64 + sa * 16);
            int rb = wn * 64 + f * 16 + i15;
            int sb = (q4 + (rb >> 1)) & 3;
            b[f] = *(const short8*)(smem + buf * 16384 + 8192 + rb * 64 + sb * 16);
        }
#pragma unroll
        for (int fm = 0; fm < 4; fm++)
#pragma unroll
            for (int fn = 0; fn < 4; fn++)
                acc[fm][fn] = __builtin_amdgcn_mfma_f32_16x16x32_bf16(
                    a[fm], b[fn], acc[fm][fn], 0, 0, 0);
    }

    if constexpr (MODE == 1) {
#pragma unroll
        for (int fm = 0; fm < 4; fm++)
#pragma unroll
            for (int reg = 0; reg < 4; reg++) {
                int gm = m0 + wm * 64 + fm * 16 + q4 * 4 + reg;
#pragma unroll
                for (int fn = 0; fn < 4; fn++) {
                    int gc = c0 + wn * 64 + fn * 16 + i15;
                    out[(size_t)gm * 512 + gc] = acc[fm][fn][reg] + bias[gc];
                }
            }
    } else {
        int t = m0 >> 13;
        int rr = m0 & 8191, qg = rr >> 10, nblk = (rr >> 7) & 7;
        int h = (c0 >> 6) + wn, hq = h * 8 + qg;
        u16* fout = (u16*)(ws + (t == 0 ? WS_FQ : t == 1 ? WS_FK : WS_FV));
        float u_[4], cb_[4];
#pragma unroll
        for (int fn = 0; fn < 4; fn++) {
            int gc = c0 + wn * 64 + fn * 16 + i15;
            u_[fn] = ws[WS_U + gc]; cb_[fn] = ws[WS_CB + gc];
        }
        float rsum[4][4], rss[4][4];
        float csum[4] = {0, 0, 0, 0}, css[4] = {0, 0, 0, 0};
#pragma unroll
        for (int fm = 0; fm < 4; fm++) {
#pragma unroll
            for (int reg = 0; reg < 4; reg++) {
                int gm = m0 + wm * 64 + fm * 16 + q4 * 4 + reg;
                float2 st = *(const float2*)(ws + WS_LNST + (size_t)gm * 2);
                float mu = st.x, rs = st.y;
                int n = gm & 1023;
                float r1 = 0.f, r2 = 0.f;
#pragma unroll
                for (int fn = 0; fn < 4; fn++) {
                    float val = rs * acc[fm][fn][reg] - rs * mu * u_[fn] + cb_[fn];
                    fout[(size_t)hq * 65536 + n * 64 + fn * 16 + i15] = f2bf(val);
                    r1 += val; r2 += val * val;
                    csum[fn] += val; css[fn] += val * val;
                }
                rsum[fm][reg] = r1; rss[fm][reg] = r2;
            }
        }
        if (t < 2) {
            float* invn = ws + (t ? WS_INVNK : WS_INVNQ) + (size_t)hq * 1024;
            float* mean = ws + (t ? WS_KMEAN : WS_QMEAN) + (size_t)hq * 1024;
#pragma unroll
            for (int fm = 0; fm < 4; fm++)
#pragma unroll
                for (int reg = 0; reg < 4; reg++) {
                    float s1 = rsum[fm][reg], s2 = rss[fm][reg];
#pragma unroll
                    for (int m = 1; m < 16; m <<= 1) {
                        s1 += __shfl_xor(s1, m, 64);
                        s2 += __shfl_xor(s2, m, 64);
                    }
                    if (i15 == fm * 4 + reg) {
                        int n = (m0 & 1023) + wm * 64 + fm * 16 + q4 * 4 + reg;
                        invn[n] = rsqrtf(s2);
                        mean[n] = s1 * (1.f / 64.f);
                    }
                }
#pragma unroll
            for (int fn = 0; fn < 4; fn++) {
                float s1 = csum[fn], s2 = css[fn];
                s1 += __shfl_xor(s1, 16, 64); s1 += __shfl_xor(s1, 32, 64);
                s2 += __shfl_xor(s2, 16, 64); s2 += __shfl_xor(s2, 32, 64);
                if (q4 == fn) {
                    colred[wm][wn][fn * 16 + i15][0] = s1;
                    colred[wm][wn][fn * 16 + i15][1] = s2;
                }
            }
        }
        __syncthreads();
        if (t < 2 && wm == 0) {
            float s1 = colred[0][wn][lane][0] + colred[1][wn][lane][0];
            float s2 = colred[0][wn][lane][1] + colred[1][wn][lane][1];
            *(float2*)(ws + WS_COLP + (size_t)(((t * 64 + hq) * 8 + nblk) * 64 + lane) * 2) =
                (float2){s1, s2};
        }
    }
}

// ---------------- K3a: parallel COLP reduction -> GSUM[2][8][64][2] --------
// block (h, t): reduce COLP[t][h*8 .. h*8+7][8][64][2] over (qg, nblk)
__global__ __launch_bounds__(256) void k_gatered(float* __restrict__ ws) {
    int h = blockIdx.x, t = blockIdx.y;
    int tid = threadIdx.x;
    int c = tid & 127, rg = tid >> 7;          // c = d*2+comp, rg = row half
    const float* base = ws + WS_COLP + ((size_t)(t * 64 + h * 8) * 8) * 128;
    float s = 0.f;
#pragma unroll 8
    for (int r = rg * 32; r < rg * 32 + 32; r++) s += base[(size_t)r * 128 + c];
    __shared__ float red[2][128];
    red[rg][c] = s;
    __syncthreads();
    if (tid < 128)
        ws[WS_GSUM + ((size_t)t * 8 + h) * 128 + tid] = red[0][tid] + red[1][tid];
}

// ---------------- K3b: gate MLP + variance penalty (reads 8KB GSUM) --------
__global__ __launch_bounds__(256) void k_gate(
    const float* __restrict__ pw1, const float* __restrict__ pb1,
    const float* __restrict__ plg, const float* __restrict__ plb,
    const float* __restrict__ pw2, const float* __restrict__ pb2,
    float* __restrict__ ws) {
    __shared__ float w1[128][64];
    __shared__ float gs[2][8][128];            // [t][h][d*2+comp]
    int tid = threadIdx.x, wid = tid >> 6, lane = tid & 63;
    for (int r = wid; r < 128; r += 4) w1[r][lane] = pw1[r * 64 + lane];
    for (int i = tid; i < 2048; i += 256) ((float*)gs)[i] = ws[WS_GSUM + i];
    __syncthreads();
    if (wid != 0) return;
    float Sq = 0, SSq = 0, Sk = 0, SSk = 0;
#pragma unroll
    for (int h = 0; h < 8; h++) {
        Sq += gs[0][h][lane * 2];  SSq += gs[0][h][lane * 2 + 1];
        Sk += gs[1][h][lane * 2];  SSk += gs[1][h][lane * 2 + 1];
    }
    const float NR = 65536.f;
    float stdq = sqrtf((SSq - Sq * Sq / NR) / (NR - 1.f) + 1e-4f);
    float stdk = sqrtf((SSk - Sk * Sk / NR) / (NR - 1.f) + 1e-4f);
    float vpen = (wsum(fmaxf(1.f - stdq, 0.f)) + wsum(fmaxf(1.f - stdk, 0.f))) * (1.f / 64.f);
    float gammav = plg[lane], betav = plb[lane], w2v = pw2[lane];
    for (int h = 0; h < 8; h++) {
        float y = pb1[lane];
#pragma unroll 8
        for (int i = 0; i < 64; i++) {
            y = fmaf(gs[0][h][i * 2] * (1.f / 8192.f), w1[i][lane], y);
            y = fmaf(gs[1][h][i * 2] * (1.f / 8192.f), w1[64 + i][lane], y);
        }
        float mu = wsum(y) * (1.f / 64.f);
        float dv = y - mu;
        float var = wsum(dv * dv) * (1.f / 64.f);
        float z = dv * rsqrtf(var + 1e-5f) * gammav + betav;
        float r = fmaxf(z, 0.f);
        float sdot = wsum(r * w2v);
        if (lane == 0) {
            float wv = 1.f / (1.f + expf(-(sdot + pb2[0])));
            ws[WS_WGATE + h] = wv / (1.f + vpen);
        }
    }
}

// ---------------- K4: build M,C (64x64 per hq), split-K over 8 parts -------
__global__ __launch_bounds__(256) void k_mc(float* __restrict__ ws) {
    int part = blockIdx.x, hq = blockIdx.y;
    const u16* fk = (const u16*)(ws + WS_FK) + (size_t)hq * 65536;
    const u16* fv = (const u16*)(ws + WS_FV) + (size_t)hq * 65536;
    const float* invk = ws + WS_INVNK + (size_t)hq * 1024;
    const float* kmg = ws + WS_KMEAN + (size_t)hq * 1024;
    __shared__ float fks[64][68], fkc[64][68], fvs[64][68];
    int tid = threadIdx.x;
    int e2 = (tid & 31) * 2, d0 = (tid >> 5) * 8;
    float am[2][8], ac[2][8];
#pragma unroll
    for (int r = 0; r < 2; r++)
#pragma unroll
        for (int j = 0; j < 8; j++) { am[r][j] = 0.f; ac[r][j] = 0.f; }

    for (int ch = 0; ch < 2; ch++) {
        int m0 = part * 128 + ch * 64;
        {
            int mr = tid >> 2, cq = (tid & 3) * 16;
            float inv = invk[m0 + mr], km = kmg[m0 + mr];
            const u16* fkr = fk + (size_t)(m0 + mr) * 64 + cq;
            const u16* fvr = fv + (size_t)(m0 + mr) * 64 + cq;
            u16x8 k0v = *(const u16x8*)fkr, k1v = *(const u16x8*)(fkr + 8);
            u16x8 v0v = *(const u16x8*)fvr, v1v = *(const u16x8*)(fvr + 8);
#pragma unroll
            for (int j = 0; j < 8; j++) {
                float kf = bf2f(k0v[j]);
                fks[mr][cq + j] = kf * inv; fkc[mr][cq + j] = kf - km;
                fvs[mr][cq + j] = bf2f(v0v[j]);
                kf = bf2f(k1v[j]);
                fks[mr][cq + 8 + j] = kf * inv; fkc[mr][cq + 8 + j] = kf - km;
                fvs[mr][cq + 8 + j] = bf2f(v1v[j]);
            }
        }
        __syncthreads();
#pragma unroll 4
        for (int mm = 0; mm < 64; mm++) {
            float2 as = *(float2*)&fks[mm][e2];
            float2 av = *(float2*)&fkc[mm][e2];
            float b[8];
            *(float4*)(b) = *(float4*)&fvs[mm][d0];
            *(float4*)(b + 4) = *(float4*)&fvs[mm][d0 + 4];
#pragma unroll
            for (int j = 0; j < 8; j++) {
                am[0][j] = fmaf(as.x, b[j], am[0][j]);
                am[1][j] = fmaf(as.y, b[j], am[1][j]);
                ac[0][j] = fmaf(av.x, b[j], ac[0][j]);
                ac[1][j] = fmaf(av.y, b[j], ac[1][j]);
            }
        }
        __syncthreads();
    }
    float* pm = ws + WS_MCP + ((size_t)(0 * 8 + part) * 64 + hq) * 4096;
    float* pc = ws + WS_MCP + ((size_t)(1 * 8 + part) * 64 + hq) * 4096;
#pragma unroll
    for (int r = 0; r < 2; r++) {
        *(float4*)(pm + (e2 + r) * 64 + d0) = *(float4*)&am[r][0];
        *(float4*)(pm + (e2 + r) * 64 + d0 + 4) = *(float4*)&am[r][4];
        *(float4*)(pc + (e2 + r) * 64 + d0) = *(float4*)&ac[r][0];
        *(float4*)(pc + (e2 + r) * 64 + d0 + 4) = *(float4*)&ac[r][4];
    }
}

// ---------------- K4b: reduce split-K partials ----------------
__global__ __launch_bounds__(256) void k_mcred(float* __restrict__ ws) {
    int cell = blockIdx.x * 256 + threadIdx.x;   // < 524288
    int mat = cell >> 18, rem = cell & 262143;
    float s = 0.f;
#pragma unroll
    for (int p = 0; p < 8; p++) s += ws[WS_MCP + (size_t)(mat * 8 + p) * 262144 + rem];
    ws[WS_MBUF + (size_t)mat * 262144 + rem] = s;
}

// ---- K5: out_attn = (1-w)/nq * fq@M + (w/64)*(fq-qmean)@C  (bf16 out) ----
__global__ __launch_bounds__(256) void k_apply(float* __restrict__ ws) {
    int nt = blockIdx.x, hq = blockIdx.y;
    int h = hq >> 3, qg = hq & 7;
    __shared__ float Ms[64][68], Cs[64][68];
    int tid = threadIdx.x;
#pragma unroll
    for (int i = 0; i < 4; i++) {
        int idx = tid + 256 * i;
        int e = idx >> 4, d4 = (idx & 15) * 4;
        *(float4*)&Ms[e][d4] = *(const float4*)(ws + WS_MBUF + (size_t)hq * 4096 + e * 64 + d4);
        *(float4*)&Cs[e][d4] = *(const float4*)(ws + WS_CBUF + (size_t)hq * 4096 + e * 64 + d4);
    }
    float w = ws[WS_WGATE + h];
    float c1 = 1.f - w, c2 = w * (1.f / 64.f);
    __syncthreads();
    int wid = tid >> 6, lane = tid & 63;
    float colC = 0.f;
#pragma unroll 16
    for (int e = 0; e < 64; e++) colC += Cs[e][lane];

    const u16* fq = (const u16*)(ws + WS_FQ) + (size_t)hq * 65536;
    const float* qm = ws + WS_QMEAN + (size_t)hq * 1024;
    const float* inv = ws + WS_INVNQ + (size_t)hq * 1024;
    u16* oat = (u16*)(ws + WS_OATT);
    int nb = nt * 128 + wid * 32;
    for (int g = 0; g < 8; g++) {
        int n = nb + g * 4;
        float a0 = bf2f(fq[(size_t)(n + 0) * 64 + lane]);
        float a1 = bf2f(fq[(size_t)(n + 1) * 64 + lane]);
        float a2 = bf2f(fq[(size_t)(n + 2) * 64 + lane]);
        float a3 = bf2f(fq[(size_t)(n + 3) * 64 + lane]);
        float m0a = 0, m1a = 0, m2a = 0, m3a = 0;
        float c0a = 0, c1a = 0, c2a = 0, c3a = 0;
#pragma unroll 16
        for (int e = 0; e < 64; e++) {
            float mv = Ms[e][lane], cv = Cs[e][lane];
            float b0 = rdlane(a0, e), b1 = rdlane(a1, e);
            float b2 = rdlane(a2, e), b3 = rdlane(a3, e);
            m0a = fmaf(b0, mv, m0a); m1a = fmaf(b1, mv, m1a);
            m2a = fmaf(b2, mv, m2a); m3a = fmaf(b3, mv, m3a);
            c0a = fmaf(b0, cv, c0a); c1a = fmaf(b1, cv, c1a);
            c2a = fmaf(b2, cv, c2a); c3a = fmaf(b3, cv, c3a);
        }
#pragma unroll
        for (int r = 0; r < 4; r++) {
            float ma = (r == 0) ? m0a : (r == 1) ? m1a : (r == 2) ? m2a : m3a;
            float ca = (r == 0) ? c0a : (r == 1) ? c1a : (r == 2) ? c2a : c3a;
            float qmv = qm[n + r], invv = inv[n + r];
            float val = c1 * invv * ma + c2 * (ca - qmv * colC);
            oat[((size_t)qg * 1024 + n + r) * 512 + h * 64 + lane] = f2bf(val);
        }
    }
}

// ---------------- host launch ----------------
extern "C" void kernel_launch(void* const* d_in, const int* in_sizes, int n_in,
                              void* d_out, int out_size, void* d_ws, size_t ws_size,
                              hipStream_t stream) {
    (void)in_sizes; (void)n_in; (void)out_size; (void)ws_size;
    const float* q = (const float*)d_in[0];
    const float* k = (const float*)d_in[1];
    const float* v = (const float*)d_in[2];
    const float* ln_g = (const float*)d_in[3];
    const float* ln_b = (const float*)d_in[4];
    const float* w_in = (const float*)d_in[5];
    const float* p_w1 = (const float*)d_in[6];
    const float* p_b1 = (const float*)d_in[7];
    const float* p_ln_g = (const float*)d_in[8];
    const float* p_ln_b = (const float*)d_in[9];
    const float* p_w2 = (const float*)d_in[10];
    const float* p_b2 = (const float*)d_in[11];
    const float* w_out = (const float*)d_in[12];
    const float* b_out = (const float*)d_in[13];
    float* ws = (float*)d_ws;
    float* out = (float*)d_out;

    k_lnstats<<<6144, 256, 0, stream>>>(q, k, v, ws);
    k_prep_t<1><<<dim3(8, 8), 256, 0, stream>>>(w_in, ln_g, (u16*)(ws + WS_WPT), ws + WS_WTF32);
    k_prep_t<0><<<dim3(8, 8), 256, 0, stream>>>(w_out, nullptr, (u16*)(ws + WS_WOT), nullptr);
    k_prep_u<<<128, 256, 0, stream>>>(ln_g, ln_b, ws);
    k_gemm<0, 96><<<dim3(4, 192), 256, 0, stream>>>((const u16*)(ws + WS_XBF),
                                                    (const u16*)(ws + WS_WPT), ws, nullptr, nullptr);
    k_gatered<<<dim3(8, 2), 256, 0, stream>>>(ws);
    k_gate<<<1, 256, 0, stream>>>(p_w1, p_b1, p_ln_g, p_ln_b, p_w2, p_b2, ws);
    k_mc<<<dim3(8, 64), 256, 0, stream>>>(ws);
    k_mcred<<<2048, 256, 0, stream>>>(ws);
    k_apply<<<dim3(8, 64), 256, 0, stream>>>(ws);
    k_gemm<1, 32><<<dim3(4, 64), 256, 0, stream>>>((const u16*)(ws + WS_OATT),
                                                   (const u16*)(ws + WS_WOT), ws, out, b_out);
}

// Round 5
// 148.409 us; speedup vs baseline: 4.1623x; 1.0746x over previous
//
#include <hip/hip_runtime.h>
#include <cstdint>

// ---------------- problem constants ----------------
// QG=8, N=1024, DIM=512, H=8, D=64; rows/tensor=8192; HQ=64
// f layout: [hq][n][d] (bf16), idx = hq*65536 + n*64 + d

typedef unsigned short u16;
typedef unsigned int u32;
typedef __attribute__((ext_vector_type(8))) unsigned short u16x8;
typedef __attribute__((ext_vector_type(4))) unsigned short u16x4;
typedef __attribute__((ext_vector_type(8))) short short8;
typedef __attribute__((ext_vector_type(4))) float floatx4;

// ---------------- workspace layout (float offsets) ----------------
#define WS_XBF     0LL          // bf16 [24576][512]  (q,k,v stacked)
#define WS_MCP     0LL          // f32 [2][8][64][4096]  (aliases XBF, used after)
#define WS_OATT    4194304LL    // bf16 [8192][512]      (aliases XBF tail, after MCP dead)
#define WS_WPT     6291456LL    // bf16 W'T [512][512]
#define WS_WOT     6422528LL    // bf16 w_outT [512][512]
#define WS_U       6553600LL    // f32 [512]  g@W_in
#define WS_CB      6554112LL    // f32 [512]  b@W_in
#define WS_LNST    6554624LL    // f32 [24576][2] (mu, rsigma)
#define WS_FQ      6603776LL    // bf16 [64][1024][64]
#define WS_FK      8700928LL
#define WS_FV      10798080LL
#define WS_INVNQ   12895232LL   // f32 [64][1024]
#define WS_INVNK   12960768LL
#define WS_QMEAN   13026304LL
#define WS_KMEAN   13091840LL
#define WS_COLP    13157376LL   // f32 [2][64][8][64][2] (sum, sumsq)
#define WS_WGATE   13288448LL   // f32 [8] (+pad)
#define WS_MBUF    13288512LL   // f32 [64][64][64]
#define WS_WTF32   13288512LL   // f32 WT [512][512] (aliases MBUF, prep-phase only)
#define WS_GSUM    13288512LL   // f32 [2][8][64][2] (aliases MBUF; live gatered->gate only)
#define WS_CBUF    13550656LL   // f32 [64][64][64]   (end = 13812800 fl = 55.3 MB)

__device__ __forceinline__ float wsum(float v) {
#pragma unroll
    for (int m = 32; m; m >>= 1) v += __shfl_xor(v, m, 64);
    return v;
}
__device__ __forceinline__ float rdlane(float v, int l) {
    return __int_as_float(__builtin_amdgcn_readlane(__float_as_int(v), l));
}
__device__ __forceinline__ u16 f2bf(float f) {
    u32 u = __float_as_uint(f);
    u32 r = u + 0x7fffu + ((u >> 16) & 1u);
    return (u16)(r >> 16);
}
__device__ __forceinline__ float bf2f(u16 u) {
    return __uint_as_float(((u32)u) << 16);
}

// ---------------- K0: LN row stats over DIM=512 + bf16 copy ----------------
__global__ __launch_bounds__(256) void k_lnstats(
    const float* __restrict__ q, const float* __restrict__ k,
    const float* __restrict__ v, float* __restrict__ ws) {
    int wid = threadIdx.x >> 6, lane = threadIdx.x & 63;
    int row = blockIdx.x * 4 + wid;            // 0..24575
    int t = row >> 13, r = row & 8191;
    const float* src = (t == 0) ? q : ((t == 1) ? k : v);
    const float4* p = (const float4*)(src + (size_t)r * 512) + lane * 2;
    float4 a = p[0], b = p[1];
    u16x8 o;
    o[0] = f2bf(a.x); o[1] = f2bf(a.y); o[2] = f2bf(a.z); o[3] = f2bf(a.w);
    o[4] = f2bf(b.x); o[5] = f2bf(b.y); o[6] = f2bf(b.z); o[7] = f2bf(b.w);
    *(u16x8*)((u16*)(ws + WS_XBF) + (size_t)row * 512 + lane * 8) = o;
    float s = a.x + a.y + a.z + a.w + b.x + b.y + b.z + b.w;
    float ss = a.x * a.x + a.y * a.y + a.z * a.z + a.w * a.w +
               b.x * b.x + b.y * b.y + b.z * b.z + b.w * b.w;
    s = wsum(s); ss = wsum(ss);
    if (lane == 0) {
        float mu = s * (1.f / 512.f);
        float var = ss * (1.f / 512.f) - mu * mu;
        ws[WS_LNST + (size_t)row * 2] = mu;
        ws[WS_LNST + (size_t)row * 2 + 1] = rsqrtf(var + 1e-5f);
    }
}

// ---------------- prep: transposed (scaled) bf16 weights ----------------
template <int SCALE>
__global__ __launch_bounds__(256) void k_prep_t(
    const float* __restrict__ W, const float* __restrict__ g,
    u16* __restrict__ Tb, float* __restrict__ Tf) {
    __shared__ float tile[64][65];
    int k0 = blockIdx.x * 64, j0 = blockIdx.y * 64;
    int tid = threadIdx.x;
    int c = (tid & 15) * 4, r0 = tid >> 4;
#pragma unroll
    for (int p = 0; p < 4; p++) {
        int r = r0 + p * 16;
        *(float4*)&tile[r][c] = *(const float4*)(W + (size_t)(k0 + r) * 512 + j0 + c);
    }
    __syncthreads();
    int kc = (tid & 15) * 4, jr0 = tid >> 4;
#pragma unroll
    for (int p = 0; p < 4; p++) {
        int jr = jr0 + p * 16;
        float v0 = tile[kc + 0][jr], v1 = tile[kc + 1][jr];
        float v2 = tile[kc + 2][jr], v3 = tile[kc + 3][jr];
        if (SCALE) {
            *(float4*)(Tf + (size_t)(j0 + jr) * 512 + k0 + kc) = (float4){v0, v1, v2, v3};
            v0 *= g[k0 + kc + 0]; v1 *= g[k0 + kc + 1];
            v2 *= g[k0 + kc + 2]; v3 *= g[k0 + kc + 3];
        }
        u16x4 ob = {f2bf(v0), f2bf(v1), f2bf(v2), f2bf(v3)};
        *(u16x4*)(Tb + (size_t)(j0 + jr) * 512 + k0 + kc) = ob;
    }
}

// ---------------- prep2: u = g@W, cb = b@W (from WT f32) ----------------
__global__ __launch_bounds__(256) void k_prep_u(
    const float* __restrict__ g, const float* __restrict__ b, float* __restrict__ ws) {
    int wid = threadIdx.x >> 6, lane = threadIdx.x & 63;
    int j = blockIdx.x * 4 + wid;              // 0..511
    const float* Tf = ws + WS_WTF32 + (size_t)j * 512;
    float su = 0.f, sc = 0.f;
#pragma unroll
    for (int m = 0; m < 8; m++) {
        int k = lane * 8 + m;
        float w = Tf[k];
        su += g[k] * w; sc += b[k] * w;
    }
    su = wsum(su); sc = wsum(sc);
    if (lane == 0) { ws[WS_U + j] = su; ws[WS_CB + j] = sc; }
}

// ---------------- bf16 MFMA GEMM, 128x128 tile, BK=32, 8 waves -------------
// 3-stage LDS pipeline, counted vmcnt pinned with sched_barrier, XCD swizzle.
// Wave grid 2(M)x4(N); wave tile 64x32 -> 4x2 fragments.
// MODE 0 (proj): epilogue f = rs*acc - rs*mu*u + cb, bf16 scatter + fused stats
// MODE 1 (out): +bias, f32 row-major.  CPX = gridblocks/8 (per-XCD chunk).
template <int MODE, int CPX>
__global__ __launch_bounds__(512, 4) void k_gemm(
    const u16* __restrict__ A, const u16* __restrict__ B,
    float* __restrict__ ws, float* __restrict__ out, const float* __restrict__ bias) {
    __shared__ char smem[49152];               // 3 bufs x (A 8K + B 8K)
    int tid = threadIdx.x;
    int wid = tid >> 6, lane = tid & 63;
    int i15 = lane & 15, q4 = lane >> 4;
    int wm = wid >> 2, wn = wid & 3;
    // XCD-bijective swizzle: consecutive logical blocks (same A row panel) on one XCD
    int flat = blockIdx.x + (blockIdx.y << 2);
    int swz = (flat & 7) * CPX + (flat >> 3);
    int c0 = (swz & 3) * 128, m0 = (swz >> 2) * 128;

    floatx4 acc[4][2];
#pragma unroll
    for (int i = 0; i < 4; i++)
#pragma unroll
        for (int j = 0; j < 2; j++) acc[i][j] = (floatx4){0.f, 0.f, 0.f, 0.f};

    const u16* gA = A + (size_t)m0 * 512;
    const u16* gB = B + (size_t)c0 * 512;

    // each wave stages 1KB of A and 1KB of B per K-step (2 glds ops/wave)
    auto stage = [&](int ks, int buf) {
        int o = wid * 1024 + lane * 16;        // byte off in 8KB region
        int srow = o >> 6, s = (o >> 4) & 3;
        int cch = (s - (srow >> 1)) & 3;       // inverse rotation
        const u16* ga = gA + (size_t)srow * 512 + ks * 32 + cch * 8;
        const u16* gb = gB + (size_t)srow * 512 + ks * 32 + cch * 8;
        char* la = smem + buf * 16384 + wid * 1024;
        char* lb = smem + buf * 16384 + 8192 + wid * 1024;
        __builtin_amdgcn_global_load_lds(
            (const __attribute__((address_space(1))) void*)ga,
            (__attribute__((address_space(3))) void*)la, 16, 0, 0);
        __builtin_amdgcn_global_load_lds(
            (const __attribute__((address_space(1))) void*)gb,
            (__attribute__((address_space(3))) void*)lb, 16, 0, 0);
    };

    stage(0, 0);
    stage(1, 1);
    __builtin_amdgcn_sched_barrier(0);
    for (int ks = 0; ks < 16; ks++) {
        __builtin_amdgcn_sched_barrier(0);
        if (ks < 15) asm volatile("s_waitcnt vmcnt(2)" ::: "memory");
        else         asm volatile("s_waitcnt vmcnt(0)" ::: "memory");
        __builtin_amdgcn_s_barrier();
        __builtin_amdgcn_sched_barrier(0);
        if (ks + 2 < 16) stage(ks + 2, (ks + 2) % 3);
        __builtin_amdgcn_sched_barrier(0);     // pin stage: no hoist above wait
        int buf = ks % 3;
        short8 a[4], b[2];
#pragma unroll
        for (int f = 0; f < 4; f++) {
            int ra = wm * 64 + f * 16 + i15;
            int sa = (q4 + (ra >> 1)) & 3;     // rotation swizzle
            a[f] = *(const short8*)(smem + buf * 16384 + ra * 64 + sa * 16);
        }
#pragma unroll
        for (int f = 0; f < 2; f++) {
            int rb = wn * 32 + f * 16 + i15;
            int sb = (q4 + (rb >> 1)) & 3;
            b[f] = *(const short8*)(smem + buf * 16384 + 8192 + rb * 64 + sb * 16);
        }
#pragma unroll
        for (int fm = 0; fm < 4; fm++)
#pragma unroll
            for (int fn = 0; fn < 2; fn++)
                acc[fm][fn] = __builtin_amdgcn_mfma_f32_16x16x32_bf16(
                    a[fm], b[fn], acc[fm][fn], 0, 0, 0);
    }

    if constexpr (MODE == 1) {
#pragma unroll
        for (int fm = 0; fm < 4; fm++)
#pragma unroll
            for (int reg = 0; reg < 4; reg++) {
                int gm = m0 + wm * 64 + fm * 16 + q4 * 4 + reg;
#pragma unroll
                for (int fn = 0; fn < 2; fn++) {
                    int gc = c0 + wn * 32 + fn * 16 + i15;
                    out[(size_t)gm * 512 + gc] = acc[fm][fn][reg] + bias[gc];
                }
            }
    } else {
        __syncthreads();                       // smem staging dead; reuse as scratch
        float2* rowred = (float2*)smem;        // [8 waves][64 rows]
        float2* colred = (float2*)(smem + 4096);  // [8 waves][32 cols]
        int t = m0 >> 13;
        int rr = m0 & 8191, qg = rr >> 10, nblk = (rr >> 7) & 7;
        int h = (c0 >> 6) + (wn >> 1), hq = h * 8 + qg;
        int dwn = (wn & 1) * 32;
        u16* fout = (u16*)(ws + (t == 0 ? WS_FQ : t == 1 ? WS_FK : WS_FV));
        float u_[2], cb_[2];
#pragma unroll
        for (int fn = 0; fn < 2; fn++) {
            int gc = c0 + wn * 32 + fn * 16 + i15;
            u_[fn] = ws[WS_U + gc]; cb_[fn] = ws[WS_CB + gc];
        }
        float csum[2] = {0, 0}, css[2] = {0, 0};
#pragma unroll
        for (int fm = 0; fm < 4; fm++) {
#pragma unroll
            for (int reg = 0; reg < 4; reg++) {
                int gm = m0 + wm * 64 + fm * 16 + q4 * 4 + reg;
                float2 st = *(const float2*)(ws + WS_LNST + (size_t)gm * 2);
                float mu = st.x, rs = st.y;
                int n = gm & 1023;
                float r1 = 0.f, r2 = 0.f;
#pragma unroll
                for (int fn = 0; fn < 2; fn++) {
                    float val = rs * acc[fm][fn][reg] - rs * mu * u_[fn] + cb_[fn];
                    fout[(size_t)hq * 65536 + n * 64 + dwn + fn * 16 + i15] = f2bf(val);
                    r1 += val; r2 += val * val;
                    csum[fn] += val; css[fn] += val * val;
                }
                if (t < 2) {
#pragma unroll
                    for (int m = 1; m < 16; m <<= 1) {
                        r1 += __shfl_xor(r1, m, 64);
                        r2 += __shfl_xor(r2, m, 64);
                    }
                    if (i15 == fm * 4 + reg)
                        rowred[(size_t)wid * 64 + fm * 16 + q4 * 4 + reg] = (float2){r1, r2};
                }
            }
        }
        if (t < 2) {
#pragma unroll
            for (int fn = 0; fn < 2; fn++) {
                float s1 = csum[fn], s2 = css[fn];
                s1 += __shfl_xor(s1, 16, 64); s1 += __shfl_xor(s1, 32, 64);
                s2 += __shfl_xor(s2, 16, 64); s2 += __shfl_xor(s2, 32, 64);
                if (q4 == fn) colred[(size_t)wid * 32 + fn * 16 + i15] = (float2){s1, s2};
            }
        }
        __syncthreads();
        if (t < 2) {
            float* invn = ws + (t ? WS_INVNK : WS_INVNQ);
            float* mean = ws + (t ? WS_KMEAN : WS_QMEAN);
            if (tid < 256) {                   // 2 wm x 2 headpair x 64 rows
                int wmf = tid >> 7, p = (tid >> 6) & 1, r = tid & 63;
                float2 aa = rowred[(size_t)(wmf * 4 + 2 * p) * 64 + r];
                float2 bb = rowred[(size_t)(wmf * 4 + 2 * p + 1) * 64 + r];
                float s1 = aa.x + bb.x, s2 = aa.y + bb.y;
                int n = (m0 & 1023) + wmf * 64 + r;
                int hhq = ((c0 >> 6) + p) * 8 + qg;
                invn[(size_t)hhq * 1024 + n] = rsqrtf(s2);
                mean[(size_t)hhq * 1024 + n] = s1 * (1.f / 64.f);
            } else if (tid < 384) {            // 2 headpair x 64 cols
                int tt = tid - 256;
                int p = tt >> 6, d = tt & 63;
                int wnn = 2 * p + (d >> 5), loc = d & 31;
                float2 aa = colred[(size_t)(0 * 4 + wnn) * 32 + loc];
                float2 bb = colred[(size_t)(1 * 4 + wnn) * 32 + loc];
                int hhq = ((c0 >> 6) + p) * 8 + qg;
                *(float2*)(ws + WS_COLP +
                           (size_t)(((t * 64 + hhq) * 8 + nblk) * 64 + d) * 2) =
                    (float2){aa.x + bb.x, aa.y + bb.y};
            }
        }
    }
}

// ---------------- K3a: parallel COLP reduction -> GSUM[2][8][64][2] --------
// block (h, t): reduce COLP[t][h*8 .. h*8+7][8][64][2] over (qg, nblk)
__global__ __launch_bounds__(256) void k_gatered(float* __restrict__ ws) {
    int h = blockIdx.x, t = blockIdx.y;
    int tid = threadIdx.x;
    int c = tid & 127, rg = tid >> 7;          // c = d*2+comp, rg = row half
    const float* base = ws + WS_COLP + ((size_t)(t * 64 + h * 8) * 8) * 128;
    float s = 0.f;
#pragma unroll 8
    for (int r = rg * 32; r < rg * 32 + 32; r++) s += base[(size_t)r * 128 + c];
    __shared__ float red[2][128];
    red[rg][c] = s;
    __syncthreads();
    if (tid < 128)
        ws[WS_GSUM + ((size_t)t * 8 + h) * 128 + tid] = red[0][tid] + red[1][tid];
}

// ---------------- K3b: gate MLP + variance penalty (reads 8KB GSUM) --------
__global__ __launch_bounds__(256) void k_gate(
    const float* __restrict__ pw1, const float* __restrict__ pb1,
    const float* __restrict__ plg, const float* __restrict__ plb,
    const float* __restrict__ pw2, const float* __restrict__ pb2,
    float* __restrict__ ws) {
    __shared__ float w1[128][64];
    __shared__ float gs[2][8][128];            // [t][h][d*2+comp]
    int tid = threadIdx.x, wid = tid >> 6, lane = tid & 63;
    for (int r = wid; r < 128; r += 4) w1[r][lane] = pw1[r * 64 + lane];
    for (int i = tid; i < 2048; i += 256) ((float*)gs)[i] = ws[WS_GSUM + i];
    __syncthreads();
    if (wid != 0) return;
    float Sq = 0, SSq = 0, Sk = 0, SSk = 0;
#pragma unroll
    for (int h = 0; h < 8; h++) {
        Sq += gs[0][h][lane * 2];  SSq += gs[0][h][lane * 2 + 1];
        Sk += gs[1][h][lane * 2];  SSk += gs[1][h][lane * 2 + 1];
    }
    const float NR = 65536.f;
    float stdq = sqrtf((SSq - Sq * Sq / NR) / (NR - 1.f) + 1e-4f);
    float stdk = sqrtf((SSk - Sk * Sk / NR) / (NR - 1.f) + 1e-4f);
    float vpen = (wsum(fmaxf(1.f - stdq, 0.f)) + wsum(fmaxf(1.f - stdk, 0.f))) * (1.f / 64.f);
    float gammav = plg[lane], betav = plb[lane], w2v = pw2[lane];
    for (int h = 0; h < 8; h++) {
        float y = pb1[lane];
#pragma unroll 8
        for (int i = 0; i < 64; i++) {
            y = fmaf(gs[0][h][i * 2] * (1.f / 8192.f), w1[i][lane], y);
            y = fmaf(gs[1][h][i * 2] * (1.f / 8192.f), w1[64 + i][lane], y);
        }
        float mu = wsum(y) * (1.f / 64.f);
        float dv = y - mu;
        float var = wsum(dv * dv) * (1.f / 64.f);
        float z = dv * rsqrtf(var + 1e-5f) * gammav + betav;
        float r = fmaxf(z, 0.f);
        float sdot = wsum(r * w2v);
        if (lane == 0) {
            float wv = 1.f / (1.f + expf(-(sdot + pb2[0])));
            ws[WS_WGATE + h] = wv / (1.f + vpen);
        }
    }
}

// ---------------- K4: build M,C (64x64 per hq), split-K over 8 parts -------
__global__ __launch_bounds__(256) void k_mc(float* __restrict__ ws) {
    int part = blockIdx.x, hq = blockIdx.y;
    const u16* fk = (const u16*)(ws + WS_FK) + (size_t)hq * 65536;
    const u16* fv = (const u16*)(ws + WS_FV) + (size_t)hq * 65536;
    const float* invk = ws + WS_INVNK + (size_t)hq * 1024;
    const float* kmg = ws + WS_KMEAN + (size_t)hq * 1024;
    __shared__ float fks[64][68], fkc[64][68], fvs[64][68];
    int tid = threadIdx.x;
    int e2 = (tid & 31) * 2, d0 = (tid >> 5) * 8;
    float am[2][8], ac[2][8];
#pragma unroll
    for (int r = 0; r < 2; r++)
#pragma unroll
        for (int j = 0; j < 8; j++) { am[r][j] = 0.f; ac[r][j] = 0.f; }

    for (int ch = 0; ch < 2; ch++) {
        int m0 = part * 128 + ch * 64;
        {
            int mr = tid >> 2, cq = (tid & 3) * 16;
            float inv = invk[m0 + mr], km = kmg[m0 + mr];
            const u16* fkr = fk + (size_t)(m0 + mr) * 64 + cq;
            const u16* fvr = fv + (size_t)(m0 + mr) * 64 + cq;
            u16x8 k0v = *(const u16x8*)fkr, k1v = *(const u16x8*)(fkr + 8);
            u16x8 v0v = *(const u16x8*)fvr, v1v = *(const u16x8*)(fvr + 8);
#pragma unroll
            for (int j = 0; j < 8; j++) {
                float kf = bf2f(k0v[j]);
                fks[mr][cq + j] = kf * inv; fkc[mr][cq + j] = kf - km;
                fvs[mr][cq + j] = bf2f(v0v[j]);
                kf = bf2f(k1v[j]);
                fks[mr][cq + 8 + j] = kf * inv; fkc[mr][cq + 8 + j] = kf - km;
                fvs[mr][cq + 8 + j] = bf2f(v1v[j]);
            }
        }
        __syncthreads();
#pragma unroll 4
        for (int mm = 0; mm < 64; mm++) {
            float2 as = *(float2*)&fks[mm][e2];
            float2 av = *(float2*)&fkc[mm][e2];
            float b[8];
            *(float4*)(b) = *(float4*)&fvs[mm][d0];
            *(float4*)(b + 4) = *(float4*)&fvs[mm][d0 + 4];
#pragma unroll
            for (int j = 0; j < 8; j++) {
                am[0][j] = fmaf(as.x, b[j], am[0][j]);
                am[1][j] = fmaf(as.y, b[j], am[1][j]);
                ac[0][j] = fmaf(av.x, b[j], ac[0][j]);
                ac[1][j] = fmaf(av.y, b[j], ac[1][j]);
            }
        }
        __syncthreads();
    }
    float* pm = ws + WS_MCP + ((size_t)(0 * 8 + part) * 64 + hq) * 4096;
    float* pc = ws + WS_MCP + ((size_t)(1 * 8 + part) * 64 + hq) * 4096;
#pragma unroll
    for (int r = 0; r < 2; r++) {
        *(float4*)(pm + (e2 + r) * 64 + d0) = *(float4*)&am[r][0];
        *(float4*)(pm + (e2 + r) * 64 + d0 + 4) = *(float4*)&am[r][4];
        *(float4*)(pc + (e2 + r) * 64 + d0) = *(float4*)&ac[r][0];
        *(float4*)(pc + (e2 + r) * 64 + d0 + 4) = *(float4*)&ac[r][4];
    }
}

// ---------------- K4b: reduce split-K partials ----------------
__global__ __launch_bounds__(256) void k_mcred(float* __restrict__ ws) {
    int cell = blockIdx.x * 256 + threadIdx.x;   // < 524288
    int mat = cell >> 18, rem = cell & 262143;
    float s = 0.f;
#pragma unroll
    for (int p = 0; p < 8; p++) s += ws[WS_MCP + (size_t)(mat * 8 + p) * 262144 + rem];
    ws[WS_MBUF + (size_t)mat * 262144 + rem] = s;
}

// ---- K5: out_attn = (1-w)/nq * fq@M + (w/64)*(fq-qmean)@C  (bf16 out) ----
__global__ __launch_bounds__(256) void k_apply(float* __restrict__ ws) {
    int nt = blockIdx.x, hq = blockIdx.y;
    int h = hq >> 3, qg = hq & 7;
    __shared__ float Ms[64][68], Cs[64][68];
    int tid = threadIdx.x;
#pragma unroll
    for (int i = 0; i < 4; i++) {
        int idx = tid + 256 * i;
        int e = idx >> 4, d4 = (idx & 15) * 4;
        *(float4*)&Ms[e][d4] = *(const float4*)(ws + WS_MBUF + (size_t)hq * 4096 + e * 64 + d4);
        *(float4*)&Cs[e][d4] = *(const float4*)(ws + WS_CBUF + (size_t)hq * 4096 + e * 64 + d4);
    }
    float w = ws[WS_WGATE + h];
    float c1 = 1.f - w, c2 = w * (1.f / 64.f);
    __syncthreads();
    int wid = tid >> 6, lane = tid & 63;
    float colC = 0.f;
#pragma unroll 16
    for (int e = 0; e < 64; e++) colC += Cs[e][lane];

    const u16* fq = (const u16*)(ws + WS_FQ) + (size_t)hq * 65536;
    const float* qm = ws + WS_QMEAN + (size_t)hq * 1024;
    const float* inv = ws + WS_INVNQ + (size_t)hq * 1024;
    u16* oat = (u16*)(ws + WS_OATT);
    int nb = nt * 128 + wid * 32;
    for (int g = 0; g < 8; g++) {
        int n = nb + g * 4;
        float a0 = bf2f(fq[(size_t)(n + 0) * 64 + lane]);
        float a1 = bf2f(fq[(size_t)(n + 1) * 64 + lane]);
        float a2 = bf2f(fq[(size_t)(n + 2) * 64 + lane]);
        float a3 = bf2f(fq[(size_t)(n + 3) * 64 + lane]);
        float m0a = 0, m1a = 0, m2a = 0, m3a = 0;
        float c0a = 0, c1a = 0, c2a = 0, c3a = 0;
#pragma unroll 16
        for (int e = 0; e < 64; e++) {
            float mv = Ms[e][lane], cv = Cs[e][lane];
            float b0 = rdlane(a0, e), b1 = rdlane(a1, e);
            float b2 = rdlane(a2, e), b3 = rdlane(a3, e);
            m0a = fmaf(b0, mv, m0a); m1a = fmaf(b1, mv, m1a);
            m2a = fmaf(b2, mv, m2a); m3a = fmaf(b3, mv, m3a);
            c0a = fmaf(b0, cv, c0a); c1a = fmaf(b1, cv, c1a);
            c2a = fmaf(b2, cv, c2a); c3a = fmaf(b3, cv, c3a);
        }
#pragma unroll
        for (int r = 0; r < 4; r++) {
            float ma = (r == 0) ? m0a : (r == 1) ? m1a : (r == 2) ? m2a : m3a;
            float ca = (r == 0) ? c0a : (r == 1) ? c1a : (r == 2) ? c2a : c3a;
            float qmv = qm[n + r], invv = inv[n + r];
            float val = c1 * invv * ma + c2 * (ca - qmv * colC);
            oat[((size_t)qg * 1024 + n + r) * 512 + h * 64 + lane] = f2bf(val);
        }
    }
}

// ---------------- host launch ----------------
extern "C" void kernel_launch(void* const* d_in, const int* in_sizes, int n_in,
                              void* d_out, int out_size, void* d_ws, size_t ws_size,
                              hipStream_t stream) {
    (void)in_sizes; (void)n_in; (void)out_size; (void)ws_size;
    const float* q = (const float*)d_in[0];
    const float* k = (const float*)d_in[1];
    const float* v = (const float*)d_in[2];
    const float* ln_g = (const float*)d_in[3];
    const float* ln_b = (const float*)d_in[4];
    const float* w_in = (const float*)d_in[5];
    const float* p_w1 = (const float*)d_in[6];
    const float* p_b1 = (const float*)d_in[7];
    const float* p_ln_g = (const float*)d_in[8];
    const float* p_ln_b = (const float*)d_in[9];
    const float* p_w2 = (const float*)d_in[10];
    const float* p_b2 = (const float*)d_in[11];
    const float* w_out = (const float*)d_in[12];
    const float* b_out = (const float*)d_in[13];
    float* ws = (float*)d_ws;
    float* out = (float*)d_out;

    k_lnstats<<<6144, 256, 0, stream>>>(q, k, v, ws);
    k_prep_t<1><<<dim3(8, 8), 256, 0, stream>>>(w_in, ln_g, (u16*)(ws + WS_WPT), ws + WS_WTF32);
    k_prep_t<0><<<dim3(8, 8), 256, 0, stream>>>(w_out, nullptr, (u16*)(ws + WS_WOT), nullptr);
    k_prep_u<<<128, 256, 0, stream>>>(ln_g, ln_b, ws);
    k_gemm<0, 96><<<dim3(4, 192), 512, 0, stream>>>((const u16*)(ws + WS_XBF),
                                                    (const u16*)(ws + WS_WPT), ws, nullptr, nullptr);
    k_gatered<<<dim3(8, 2), 256, 0, stream>>>(ws);
    k_gate<<<1, 256, 0, stream>>>(p_w1, p_b1, p_ln_g, p_ln_b, p_w2, p_b2, ws);
    k_mc<<<dim3(8, 64), 256, 0, stream>>>(ws);
    k_mcred<<<2048, 256, 0, stream>>>(ws);
    k_apply<<<dim3(8, 64), 256, 0, stream>>>(ws);
    k_gemm<1, 32><<<dim3(4, 64), 512, 0, stream>>>((const u16*)(ws + WS_OATT),
                                                   (const u16*)(ws + WS_WOT), ws, out, b_out);
}

// Round 6
// 125.185 us; speedup vs baseline: 4.9345x; 1.1855x over previous
//
#include <hip/hip_runtime.h>
#include <cstdint>

// ---------------- problem constants ----------------
// QG=8, N=1024, DIM=512, H=8, D=64; rows/tensor=8192; HQ=64
// f layout: [hq][n][d] (bf16), idx = hq*65536 + n*64 + d

typedef unsigned short u16;
typedef unsigned int u32;
typedef __attribute__((ext_vector_type(8))) unsigned short u16x8;
typedef __attribute__((ext_vector_type(4))) unsigned short u16x4;
typedef __attribute__((ext_vector_type(8))) short short8;
typedef __attribute__((ext_vector_type(4))) float floatx4;

// ---------------- workspace layout (float offsets) ----------------
#define WS_XBF     0LL          // bf16 [24576][512]  (q,k,v stacked)
#define WS_MCP     0LL          // f32 [2][8][64][4096]  (aliases XBF, used after)
#define WS_OATT    4194304LL    // bf16 [8192][512]      (aliases XBF tail, after MCP dead)
#define WS_WPT     6291456LL    // bf16 W'T [512][512]
#define WS_WOT     6422528LL    // bf16 w_outT [512][512]
#define WS_U       6553600LL    // f32 [512]  g@W_in
#define WS_CB      6554112LL    // f32 [512]  b@W_in
#define WS_LNST    6554624LL    // f32 [24576][2] (mu, rsigma)
#define WS_FQ      6603776LL    // bf16 [64][1024][64]
#define WS_FK      8700928LL
#define WS_FV      10798080LL
#define WS_INVNQ   12895232LL   // f32 [64][1024]
#define WS_INVNK   12960768LL
#define WS_QMEAN   13026304LL
#define WS_KMEAN   13091840LL
#define WS_COLP    13157376LL   // f32 [2][64][8][64][2] (sum, sumsq)
#define WS_WGATE   13288448LL   // f32 [8] (+pad)
#define WS_WTF32   13288512LL   // f32 WT [512][512] (prep-phase only)
#define WS_GSUM    13288512LL   // f32 [2][8][64][2] (gatered->gate only)
#define WS_MTB     13288512LL   // bf16 M^T [64][64][64] (mcred->apply; after gate)
#define WS_CTB     13419584LL   // bf16 C^T [64][64][64]
#define WS_COLC    13550656LL   // f32 [64][64] colsum of C
// end = 13554752 floats = 54.2 MB

__device__ __forceinline__ float wsum(float v) {
#pragma unroll
    for (int m = 32; m; m >>= 1) v += __shfl_xor(v, m, 64);
    return v;
}
__device__ __forceinline__ u16 f2bf(float f) {
    u32 u = __float_as_uint(f);
    u32 r = u + 0x7fffu + ((u >> 16) & 1u);
    return (u16)(r >> 16);
}
__device__ __forceinline__ float bf2f(u16 u) {
    return __uint_as_float(((u32)u) << 16);
}

// ---------------- K0: LN row stats over DIM=512 + bf16 copy ----------------
__global__ __launch_bounds__(256) void k_lnstats(
    const float* __restrict__ q, const float* __restrict__ k,
    const float* __restrict__ v, float* __restrict__ ws) {
    int wid = threadIdx.x >> 6, lane = threadIdx.x & 63;
    int row = blockIdx.x * 4 + wid;            // 0..24575
    int t = row >> 13, r = row & 8191;
    const float* src = (t == 0) ? q : ((t == 1) ? k : v);
    const float4* p = (const float4*)(src + (size_t)r * 512) + lane * 2;
    float4 a = p[0], b = p[1];
    u16x8 o;
    o[0] = f2bf(a.x); o[1] = f2bf(a.y); o[2] = f2bf(a.z); o[3] = f2bf(a.w);
    o[4] = f2bf(b.x); o[5] = f2bf(b.y); o[6] = f2bf(b.z); o[7] = f2bf(b.w);
    *(u16x8*)((u16*)(ws + WS_XBF) + (size_t)row * 512 + lane * 8) = o;
    float s = a.x + a.y + a.z + a.w + b.x + b.y + b.z + b.w;
    float ss = a.x * a.x + a.y * a.y + a.z * a.z + a.w * a.w +
               b.x * b.x + b.y * b.y + b.z * b.z + b.w * b.w;
    s = wsum(s); ss = wsum(ss);
    if (lane == 0) {
        float mu = s * (1.f / 512.f);
        float var = ss * (1.f / 512.f) - mu * mu;
        ws[WS_LNST + (size_t)row * 2] = mu;
        ws[WS_LNST + (size_t)row * 2 + 1] = rsqrtf(var + 1e-5f);
    }
}

// ---------------- prep: transposed (scaled) bf16 weights ----------------
template <int SCALE>
__global__ __launch_bounds__(256) void k_prep_t(
    const float* __restrict__ W, const float* __restrict__ g,
    u16* __restrict__ Tb, float* __restrict__ Tf) {
    __shared__ float tile[64][65];
    int k0 = blockIdx.x * 64, j0 = blockIdx.y * 64;
    int tid = threadIdx.x;
    int c = (tid & 15) * 4, r0 = tid >> 4;
#pragma unroll
    for (int p = 0; p < 4; p++) {
        int r = r0 + p * 16;
        *(float4*)&tile[r][c] = *(const float4*)(W + (size_t)(k0 + r) * 512 + j0 + c);
    }
    __syncthreads();
    int kc = (tid & 15) * 4, jr0 = tid >> 4;
#pragma unroll
    for (int p = 0; p < 4; p++) {
        int jr = jr0 + p * 16;
        float v0 = tile[kc + 0][jr], v1 = tile[kc + 1][jr];
        float v2 = tile[kc + 2][jr], v3 = tile[kc + 3][jr];
        if (SCALE) {
            *(float4*)(Tf + (size_t)(j0 + jr) * 512 + k0 + kc) = (float4){v0, v1, v2, v3};
            v0 *= g[k0 + kc + 0]; v1 *= g[k0 + kc + 1];
            v2 *= g[k0 + kc + 2]; v3 *= g[k0 + kc + 3];
        }
        u16x4 ob = {f2bf(v0), f2bf(v1), f2bf(v2), f2bf(v3)};
        *(u16x4*)(Tb + (size_t)(j0 + jr) * 512 + k0 + kc) = ob;
    }
}

// ---------------- prep2: u = g@W, cb = b@W (from WT f32) ----------------
__global__ __launch_bounds__(256) void k_prep_u(
    const float* __restrict__ g, const float* __restrict__ b, float* __restrict__ ws) {
    int wid = threadIdx.x >> 6, lane = threadIdx.x & 63;
    int j = blockIdx.x * 4 + wid;              // 0..511
    const float* Tf = ws + WS_WTF32 + (size_t)j * 512;
    float su = 0.f, sc = 0.f;
#pragma unroll
    for (int m = 0; m < 8; m++) {
        int k = lane * 8 + m;
        float w = Tf[k];
        su += g[k] * w; sc += b[k] * w;
    }
    su = wsum(su); sc = wsum(sc);
    if (lane == 0) { ws[WS_U + j] = su; ws[WS_CB + j] = sc; }
}

// ---------------- bf16 MFMA GEMM, 128x128 tile, BK=32, 8 waves -------------
// 3-stage LDS pipeline, counted vmcnt pinned with sched_barrier, XCD swizzle.
// Wave grid 2(M)x4(N); wave tile 64x32 -> 4x2 fragments.
// MODE 0 (proj): epilogue f = rs*acc - rs*mu*u + cb, bf16 scatter + fused stats
// MODE 1 (out): +bias, f32 row-major.  CPX = gridblocks/8 (per-XCD chunk).
template <int MODE, int CPX>
__global__ __launch_bounds__(512, 4) void k_gemm(
    const u16* __restrict__ A, const u16* __restrict__ B,
    float* __restrict__ ws, float* __restrict__ out, const float* __restrict__ bias) {
    __shared__ char smem[49152];               // 3 bufs x (A 8K + B 8K)
    int tid = threadIdx.x;
    int wid = tid >> 6, lane = tid & 63;
    int i15 = lane & 15, q4 = lane >> 4;
    int wm = wid >> 2, wn = wid & 3;
    // XCD-bijective swizzle: consecutive logical blocks (same A row panel) on one XCD
    int flat = blockIdx.x + (blockIdx.y << 2);
    int swz = (flat & 7) * CPX + (flat >> 3);
    int c0 = (swz & 3) * 128, m0 = (swz >> 2) * 128;

    floatx4 acc[4][2];
#pragma unroll
    for (int i = 0; i < 4; i++)
#pragma unroll
        for (int j = 0; j < 2; j++) acc[i][j] = (floatx4){0.f, 0.f, 0.f, 0.f};

    const u16* gA = A + (size_t)m0 * 512;
    const u16* gB = B + (size_t)c0 * 512;

    // each wave stages 1KB of A and 1KB of B per K-step (2 glds ops/wave)
    auto stage = [&](int ks, int buf) {
        int o = wid * 1024 + lane * 16;        // byte off in 8KB region
        int srow = o >> 6, s = (o >> 4) & 3;
        int cch = (s - (srow >> 1)) & 3;       // inverse rotation
        const u16* ga = gA + (size_t)srow * 512 + ks * 32 + cch * 8;
        const u16* gb = gB + (size_t)srow * 512 + ks * 32 + cch * 8;
        char* la = smem + buf * 16384 + wid * 1024;
        char* lb = smem + buf * 16384 + 8192 + wid * 1024;
        __builtin_amdgcn_global_load_lds(
            (const __attribute__((address_space(1))) void*)ga,
            (__attribute__((address_space(3))) void*)la, 16, 0, 0);
        __builtin_amdgcn_global_load_lds(
            (const __attribute__((address_space(1))) void*)gb,
            (__attribute__((address_space(3))) void*)lb, 16, 0, 0);
    };

    stage(0, 0);
    stage(1, 1);
    __builtin_amdgcn_sched_barrier(0);
    for (int ks = 0; ks < 16; ks++) {
        __builtin_amdgcn_sched_barrier(0);
        if (ks < 15) asm volatile("s_waitcnt vmcnt(2)" ::: "memory");
        else         asm volatile("s_waitcnt vmcnt(0)" ::: "memory");
        __builtin_amdgcn_s_barrier();
        __builtin_amdgcn_sched_barrier(0);
        if (ks + 2 < 16) stage(ks + 2, (ks + 2) % 3);
        __builtin_amdgcn_sched_barrier(0);     // pin stage: no hoist above wait
        int buf = ks % 3;
        short8 a[4], b[2];
#pragma unroll
        for (int f = 0; f < 4; f++) {
            int ra = wm * 64 + f * 16 + i15;
            int sa = (q4 + (ra >> 1)) & 3;     // rotation swizzle
            a[f] = *(const short8*)(smem + buf * 16384 + ra * 64 + sa * 16);
        }
#pragma unroll
        for (int f = 0; f < 2; f++) {
            int rb = wn * 32 + f * 16 + i15;
            int sb = (q4 + (rb >> 1)) & 3;
            b[f] = *(const short8*)(smem + buf * 16384 + 8192 + rb * 64 + sb * 16);
        }
#pragma unroll
        for (int fm = 0; fm < 4; fm++)
#pragma unroll
            for (int fn = 0; fn < 2; fn++)
                acc[fm][fn] = __builtin_amdgcn_mfma_f32_16x16x32_bf16(
                    a[fm], b[fn], acc[fm][fn], 0, 0, 0);
    }

    if constexpr (MODE == 1) {
#pragma unroll
        for (int fm = 0; fm < 4; fm++)
#pragma unroll
            for (int reg = 0; reg < 4; reg++) {
                int gm = m0 + wm * 64 + fm * 16 + q4 * 4 + reg;
#pragma unroll
                for (int fn = 0; fn < 2; fn++) {
                    int gc = c0 + wn * 32 + fn * 16 + i15;
                    out[(size_t)gm * 512 + gc] = acc[fm][fn][reg] + bias[gc];
                }
            }
    } else {
        __syncthreads();                       // smem staging dead; reuse as scratch
        float2* rowred = (float2*)smem;        // [8 waves][64 rows]
        float2* colred = (float2*)(smem + 4096);  // [8 waves][32 cols]
        int t = m0 >> 13;
        int rr = m0 & 8191, qg = rr >> 10, nblk = (rr >> 7) & 7;
        int h = (c0 >> 6) + (wn >> 1), hq = h * 8 + qg;
        int dwn = (wn & 1) * 32;
        u16* fout = (u16*)(ws + (t == 0 ? WS_FQ : t == 1 ? WS_FK : WS_FV));
        float u_[2], cb_[2];
#pragma unroll
        for (int fn = 0; fn < 2; fn++) {
            int gc = c0 + wn * 32 + fn * 16 + i15;
            u_[fn] = ws[WS_U + gc]; cb_[fn] = ws[WS_CB + gc];
        }
        float csum[2] = {0, 0}, css[2] = {0, 0};
#pragma unroll
        for (int fm = 0; fm < 4; fm++) {
#pragma unroll
            for (int reg = 0; reg < 4; reg++) {
                int gm = m0 + wm * 64 + fm * 16 + q4 * 4 + reg;
                float2 st = *(const float2*)(ws + WS_LNST + (size_t)gm * 2);
                float mu = st.x, rs = st.y;
                int n = gm & 1023;
                float r1 = 0.f, r2 = 0.f;
#pragma unroll
                for (int fn = 0; fn < 2; fn++) {
                    float val = rs * acc[fm][fn][reg] - rs * mu * u_[fn] + cb_[fn];
                    fout[(size_t)hq * 65536 + n * 64 + dwn + fn * 16 + i15] = f2bf(val);
                    r1 += val; r2 += val * val;
                    csum[fn] += val; css[fn] += val * val;
                }
                if (t < 2) {
#pragma unroll
                    for (int m = 1; m < 16; m <<= 1) {
                        r1 += __shfl_xor(r1, m, 64);
                        r2 += __shfl_xor(r2, m, 64);
                    }
                    if (i15 == fm * 4 + reg)
                        rowred[(size_t)wid * 64 + fm * 16 + q4 * 4 + reg] = (float2){r1, r2};
                }
            }
        }
        if (t < 2) {
#pragma unroll
            for (int fn = 0; fn < 2; fn++) {
                float s1 = csum[fn], s2 = css[fn];
                s1 += __shfl_xor(s1, 16, 64); s1 += __shfl_xor(s1, 32, 64);
                s2 += __shfl_xor(s2, 16, 64); s2 += __shfl_xor(s2, 32, 64);
                if (q4 == fn) colred[(size_t)wid * 32 + fn * 16 + i15] = (float2){s1, s2};
            }
        }
        __syncthreads();
        if (t < 2) {
            float* invn = ws + (t ? WS_INVNK : WS_INVNQ);
            float* mean = ws + (t ? WS_KMEAN : WS_QMEAN);
            if (tid < 256) {                   // 2 wm x 2 headpair x 64 rows
                int wmf = tid >> 7, p = (tid >> 6) & 1, r = tid & 63;
                float2 aa = rowred[(size_t)(wmf * 4 + 2 * p) * 64 + r];
                float2 bb = rowred[(size_t)(wmf * 4 + 2 * p + 1) * 64 + r];
                float s1 = aa.x + bb.x, s2 = aa.y + bb.y;
                int n = (m0 & 1023) + wmf * 64 + r;
                int hhq = ((c0 >> 6) + p) * 8 + qg;
                invn[(size_t)hhq * 1024 + n] = rsqrtf(s2);
                mean[(size_t)hhq * 1024 + n] = s1 * (1.f / 64.f);
            } else if (tid < 384) {            // 2 headpair x 64 cols
                int tt = tid - 256;
                int p = tt >> 6, d = tt & 63;
                int wnn = 2 * p + (d >> 5), loc = d & 31;
                float2 aa = colred[(size_t)(0 * 4 + wnn) * 32 + loc];
                float2 bb = colred[(size_t)(1 * 4 + wnn) * 32 + loc];
                int hhq = ((c0 >> 6) + p) * 8 + qg;
                *(float2*)(ws + WS_COLP +
                           (size_t)(((t * 64 + hhq) * 8 + nblk) * 64 + d) * 2) =
                    (float2){aa.x + bb.x, aa.y + bb.y};
            }
        }
    }
}

// ---------------- K3a: parallel COLP reduction -> GSUM[2][8][64][2] --------
__global__ __launch_bounds__(256) void k_gatered(float* __restrict__ ws) {
    int h = blockIdx.x, t = blockIdx.y;
    int tid = threadIdx.x;
    int c = tid & 127, rg = tid >> 7;          // c = d*2+comp, rg = row half
    const float* base = ws + WS_COLP + ((size_t)(t * 64 + h * 8) * 8) * 128;
    float s = 0.f;
#pragma unroll 8
    for (int r = rg * 32; r < rg * 32 + 32; r++) s += base[(size_t)r * 128 + c];
    __shared__ float red[2][128];
    red[rg][c] = s;
    __syncthreads();
    if (tid < 128)
        ws[WS_GSUM + ((size_t)t * 8 + h) * 128 + tid] = red[0][tid] + red[1][tid];
}

// ---------------- K3b: gate MLP + variance penalty (reads 8KB GSUM) --------
__global__ __launch_bounds__(256) void k_gate(
    const float* __restrict__ pw1, const float* __restrict__ pb1,
    const float* __restrict__ plg, const float* __restrict__ plb,
    const float* __restrict__ pw2, const float* __restrict__ pb2,
    float* __restrict__ ws) {
    __shared__ float w1[128][64];
    __shared__ float gs[2][8][128];            // [t][h][d*2+comp]
    int tid = threadIdx.x, wid = tid >> 6, lane = tid & 63;
    for (int r = wid; r < 128; r += 4) w1[r][lane] = pw1[r * 64 + lane];
    for (int i = tid; i < 2048; i += 256) ((float*)gs)[i] = ws[WS_GSUM + i];
    __syncthreads();
    if (wid != 0) return;
    float Sq = 0, SSq = 0, Sk = 0, SSk = 0;
#pragma unroll
    for (int h = 0; h < 8; h++) {
        Sq += gs[0][h][lane * 2];  SSq += gs[0][h][lane * 2 + 1];
        Sk += gs[1][h][lane * 2];  SSk += gs[1][h][lane * 2 + 1];
    }
    const float NR = 65536.f;
    float stdq = sqrtf((SSq - Sq * Sq / NR) / (NR - 1.f) + 1e-4f);
    float stdk = sqrtf((SSk - Sk * Sk / NR) / (NR - 1.f) + 1e-4f);
    float vpen = (wsum(fmaxf(1.f - stdq, 0.f)) + wsum(fmaxf(1.f - stdk, 0.f))) * (1.f / 64.f);
    float gammav = plg[lane], betav = plb[lane], w2v = pw2[lane];
    for (int h = 0; h < 8; h++) {
        float y = pb1[lane];
#pragma unroll 8
        for (int i = 0; i < 64; i++) {
            y = fmaf(gs[0][h][i * 2] * (1.f / 8192.f), w1[i][lane], y);
            y = fmaf(gs[1][h][i * 2] * (1.f / 8192.f), w1[64 + i][lane], y);
        }
        float mu = wsum(y) * (1.f / 64.f);
        float dv = y - mu;
        float var = wsum(dv * dv) * (1.f / 64.f);
        float z = dv * rsqrtf(var + 1e-5f) * gammav + betav;
        float r = fmaxf(z, 0.f);
        float sdot = wsum(r * w2v);
        if (lane == 0) {
            float wv = 1.f / (1.f + expf(-(sdot + pb2[0])));
            ws[WS_WGATE + h] = wv / (1.f + vpen);
        }
    }
}

// ---------------- K4: build M,C (64x64 per hq), split-K over 8 parts -------
__global__ __launch_bounds__(256) void k_mc(float* __restrict__ ws) {
    int part = blockIdx.x, hq = blockIdx.y;
    const u16* fk = (const u16*)(ws + WS_FK) + (size_t)hq * 65536;
    const u16* fv = (const u16*)(ws + WS_FV) + (size_t)hq * 65536;
    const float* invk = ws + WS_INVNK + (size_t)hq * 1024;
    const float* kmg = ws + WS_KMEAN + (size_t)hq * 1024;
    __shared__ float fks[64][68], fkc[64][68], fvs[64][68];
    int tid = threadIdx.x;
    int e2 = (tid & 31) * 2, d0 = (tid >> 5) * 8;
    float am[2][8], ac[2][8];
#pragma unroll
    for (int r = 0; r < 2; r++)
#pragma unroll
        for (int j = 0; j < 8; j++) { am[r][j] = 0.f; ac[r][j] = 0.f; }

    for (int ch = 0; ch < 2; ch++) {
        int m0 = part * 128 + ch * 64;
        {
            int mr = tid >> 2, cq = (tid & 3) * 16;
            float inv = invk[m0 + mr], km = kmg[m0 + mr];
            const u16* fkr = fk + (size_t)(m0 + mr) * 64 + cq;
            const u16* fvr = fv + (size_t)(m0 + mr) * 64 + cq;
            u16x8 k0v = *(const u16x8*)fkr, k1v = *(const u16x8*)(fkr + 8);
            u16x8 v0v = *(const u16x8*)fvr, v1v = *(const u16x8*)(fvr + 8);
#pragma unroll
            for (int j = 0; j < 8; j++) {
                float kf = bf2f(k0v[j]);
                fks[mr][cq + j] = kf * inv; fkc[mr][cq + j] = kf - km;
                fvs[mr][cq + j] = bf2f(v0v[j]);
                kf = bf2f(k1v[j]);
                fks[mr][cq + 8 + j] = kf * inv; fkc[mr][cq + 8 + j] = kf - km;
                fvs[mr][cq + 8 + j] = bf2f(v1v[j]);
            }
        }
        __syncthreads();
#pragma unroll 4
        for (int mm = 0; mm < 64; mm++) {
            float2 as = *(float2*)&fks[mm][e2];
            float2 av = *(float2*)&fkc[mm][e2];
            float b[8];
            *(float4*)(b) = *(float4*)&fvs[mm][d0];
            *(float4*)(b + 4) = *(float4*)&fvs[mm][d0 + 4];
#pragma unroll
            for (int j = 0; j < 8; j++) {
                am[0][j] = fmaf(as.x, b[j], am[0][j]);
                am[1][j] = fmaf(as.y, b[j], am[1][j]);
                ac[0][j] = fmaf(av.x, b[j], ac[0][j]);
                ac[1][j] = fmaf(av.y, b[j], ac[1][j]);
            }
        }
        __syncthreads();
    }
    float* pm = ws + WS_MCP + ((size_t)(0 * 8 + part) * 64 + hq) * 4096;
    float* pc = ws + WS_MCP + ((size_t)(1 * 8 + part) * 64 + hq) * 4096;
#pragma unroll
    for (int r = 0; r < 2; r++) {
        *(float4*)(pm + (e2 + r) * 64 + d0) = *(float4*)&am[r][0];
        *(float4*)(pm + (e2 + r) * 64 + d0 + 4) = *(float4*)&am[r][4];
        *(float4*)(pc + (e2 + r) * 64 + d0) = *(float4*)&ac[r][0];
        *(float4*)(pc + (e2 + r) * 64 + d0 + 4) = *(float4*)&ac[r][4];
    }
}

// ------- K4b: reduce split-K partials -> bf16 M^T,C^T + colC(f32) ----------
// one block per hq; coalesced partial reads, LDS transpose, vector bf16 writes
__global__ __launch_bounds__(256) void k_mcred(float* __restrict__ ws) {
    int hq = blockIdx.x;
    int tid = threadIdx.x;
    __shared__ float tile[2][64][65];
    __shared__ float cred[4][64];
    int e = tid & 63, dc = tid >> 6;
#pragma unroll
    for (int mat = 0; mat < 2; mat++) {
#pragma unroll
        for (int dq = 0; dq < 4; dq++) {
            int d0 = dc * 16 + dq * 4;
            float4 s = {0.f, 0.f, 0.f, 0.f};
#pragma unroll
            for (int p = 0; p < 8; p++) {
                const float* src = ws + WS_MCP +
                    ((size_t)(mat * 8 + p) * 64 + hq) * 4096 + e * 64 + d0;
                float4 vv = *(const float4*)src;
                s.x += vv.x; s.y += vv.y; s.z += vv.z; s.w += vv.w;
            }
            tile[mat][e][d0 + 0] = s.x; tile[mat][e][d0 + 1] = s.y;
            tile[mat][e][d0 + 2] = s.z; tile[mat][e][d0 + 3] = s.w;
        }
    }
    __syncthreads();
    int d = tid & 63, ec = tid >> 6;
    float cp = 0.f;
#pragma unroll
    for (int i = 0; i < 16; i++) cp += tile[1][ec * 16 + i][d];
    cred[ec][d] = cp;
#pragma unroll
    for (int mat = 0; mat < 2; mat++) {
        u16x8 p0, p1;
#pragma unroll
        for (int i = 0; i < 8; i++) {
            p0[i] = f2bf(tile[mat][ec * 16 + i][d]);
            p1[i] = f2bf(tile[mat][ec * 16 + 8 + i][d]);
        }
        u16* dst = (u16*)(ws + (mat ? WS_CTB : WS_MTB)) + (size_t)hq * 4096 + d * 64 + ec * 16;
        *(u16x8*)dst = p0;
        *(u16x8*)(dst + 8) = p1;
    }
    __syncthreads();
    if (tid < 64)
        ws[WS_COLC + (size_t)hq * 64 + tid] =
            cred[0][tid] + cred[1][tid] + cred[2][tid] + cred[3][tid];
}

// ---- K5 (MFMA): out_attn = c1*inv*(fq@M) + c2*(fq@C - qm*colC)  bf16 out ---
// block = 4 waves, 256 rows; grid (4, 64 hq). B-frags from XOR-swizzled LDS.
__global__ __launch_bounds__(256) void k_apply(float* __restrict__ ws) {
    int nt = blockIdx.x, hq = blockIdx.y;
    int h = hq >> 3, qg = hq & 7;
    __shared__ u16 mt[2][4096];                // swizzled M^T, C^T (8KB each)
    __shared__ float invqm[256][2];
    __shared__ u16 outs[256][66];              // +2 pad: bank-rotate rows
    int tid = threadIdx.x, wid = tid >> 6, lane = tid & 63;
    int i15 = lane & 15, q4 = lane >> 4;
#pragma unroll
    for (int mat = 0; mat < 2; mat++) {
        const u16* src = (const u16*)(ws + (mat ? WS_CTB : WS_MTB)) + (size_t)hq * 4096;
#pragma unroll
        for (int it = 0; it < 2; it++) {
            int i = tid + it * 256;            // 16B chunk id, 512 total
            int d = i >> 3, c8 = i & 7;
            u16x8 v = *(const u16x8*)(src + i * 8);
            int byte = d * 128 + ((c8 * 16) ^ ((d & 7) << 4));
            *(u16x8*)((char*)&mt[mat][0] + byte) = v;
        }
    }
    int R0 = nt * 256;
    invqm[tid][0] = ws[WS_INVNQ + (size_t)hq * 1024 + R0 + tid];
    invqm[tid][1] = ws[WS_QMEAN + (size_t)hq * 1024 + R0 + tid];
    float wv = ws[WS_WGATE + h];
    float c1 = 1.f - wv, c2 = wv * (1.f / 64.f);
    float colc[4];
#pragma unroll
    for (int fn = 0; fn < 4; fn++)
        colc[fn] = ws[WS_COLC + (size_t)hq * 64 + fn * 16 + i15];
    __syncthreads();
    const u16* fq = (const u16*)(ws + WS_FQ) + (size_t)hq * 65536 +
                    (size_t)(R0 + wid * 64) * 64;
    floatx4 aM[4][4], aC[4][4];
#pragma unroll
    for (int i = 0; i < 4; i++)
#pragma unroll
        for (int j = 0; j < 4; j++) {
            aM[i][j] = (floatx4){0.f, 0.f, 0.f, 0.f};
            aC[i][j] = (floatx4){0.f, 0.f, 0.f, 0.f};
        }
#pragma unroll
    for (int ks = 0; ks < 2; ks++) {
        short8 a[4], bM[4], bC[4];
#pragma unroll
        for (int f = 0; f < 4; f++)
            a[f] = *(const short8*)(fq + (size_t)(f * 16 + i15) * 64 + q4 * 8 + ks * 32);
#pragma unroll
        for (int f = 0; f < 4; f++) {
            int col = f * 16 + i15;
            int byte = col * 128 + ((q4 * 16 + ks * 64) ^ ((col & 7) << 4));
            bM[f] = *(const short8*)((char*)&mt[0][0] + byte);
            bC[f] = *(const short8*)((char*)&mt[1][0] + byte);
        }
#pragma unroll
        for (int fm = 0; fm < 4; fm++)
#pragma unroll
            for (int fn = 0; fn < 4; fn++) {
                aM[fm][fn] = __builtin_amdgcn_mfma_f32_16x16x32_bf16(
                    a[fm], bM[fn], aM[fm][fn], 0, 0, 0);
                aC[fm][fn] = __builtin_amdgcn_mfma_f32_16x16x32_bf16(
                    a[fm], bC[fn], aC[fm][fn], 0, 0, 0);
            }
    }
#pragma unroll
    for (int fm = 0; fm < 4; fm++)
#pragma unroll
        for (int reg = 0; reg < 4; reg++) {
            int rloc = wid * 64 + fm * 16 + q4 * 4 + reg;
            float iv = invqm[rloc][0], qmv = invqm[rloc][1];
#pragma unroll
            for (int fn = 0; fn < 4; fn++) {
                float val = c1 * iv * aM[fm][fn][reg] +
                            c2 * (aC[fm][fn][reg] - qmv * colc[fn]);
                outs[rloc][fn * 16 + i15] = f2bf(val);
            }
        }
    __syncthreads();
    u16* oat = (u16*)(ws + WS_OATT);
#pragma unroll
    for (int it = 0; it < 8; it++) {
        int c = tid + it * 256;                // 16B chunk id, 2048 total
        int row = c >> 3, c8 = (c & 7) * 8;
        u16x8 v = *(const u16x8*)&outs[row][c8];
        *(u16x8*)(oat + ((size_t)qg * 1024 + R0 + row) * 512 + h * 64 + c8) = v;
    }
}

// ---------------- host launch ----------------
extern "C" void kernel_launch(void* const* d_in, const int* in_sizes, int n_in,
                              void* d_out, int out_size, void* d_ws, size_t ws_size,
                              hipStream_t stream) {
    (void)in_sizes; (void)n_in; (void)out_size; (void)ws_size;
    const float* q = (const float*)d_in[0];
    const float* k = (const float*)d_in[1];
    const float* v = (const float*)d_in[2];
    const float* ln_g = (const float*)d_in[3];
    const float* ln_b = (const float*)d_in[4];
    const float* w_in = (const float*)d_in[5];
    const float* p_w1 = (const float*)d_in[6];
    const float* p_b1 = (const float*)d_in[7];
    const float* p_ln_g = (const float*)d_in[8];
    const float* p_ln_b = (const float*)d_in[9];
    const float* p_w2 = (const float*)d_in[10];
    const float* p_b2 = (const float*)d_in[11];
    const float* w_out = (const float*)d_in[12];
    const float* b_out = (const float*)d_in[13];
    float* ws = (float*)d_ws;
    float* out = (float*)d_out;

    k_lnstats<<<6144, 256, 0, stream>>>(q, k, v, ws);
    k_prep_t<1><<<dim3(8, 8), 256, 0, stream>>>(w_in, ln_g, (u16*)(ws + WS_WPT), ws + WS_WTF32);
    k_prep_t<0><<<dim3(8, 8), 256, 0, stream>>>(w_out, nullptr, (u16*)(ws + WS_WOT), nullptr);
    k_prep_u<<<128, 256, 0, stream>>>(ln_g, ln_b, ws);
    k_gemm<0, 96><<<dim3(4, 192), 512, 0, stream>>>((const u16*)(ws + WS_XBF),
                                                    (const u16*)(ws + WS_WPT), ws, nullptr, nullptr);
    k_gatered<<<dim3(8, 2), 256, 0, stream>>>(ws);
    k_gate<<<1, 256, 0, stream>>>(p_w1, p_b1, p_ln_g, p_ln_b, p_w2, p_b2, ws);
    k_mc<<<dim3(8, 64), 256, 0, stream>>>(ws);
    k_mcred<<<64, 256, 0, stream>>>(ws);
    k_apply<<<dim3(4, 64), 256, 0, stream>>>(ws);
    k_gemm<1, 32><<<dim3(4, 64), 512, 0, stream>>>((const u16*)(ws + WS_OATT),
                                                   (const u16*)(ws + WS_WOT), ws, out, b_out);
}